// Round 7
// baseline (257.636 us; speedup 1.0000x reference)
//
#include <hip/hip_runtime.h>
#include <hip/hip_bf16.h>
#include <stdint.h>

// RWKV7-like block: B=4 T=2048 D=1024 NH=16 HD=64.
// Inputs fp32 (order x,Wr,Wk,Wv,Ww,Wo); OUTPUT FP32. Verified R7-R9,R13,R16 (absmax .0195).
//
// R17: keep R16's time-major tail (scans at full MLP; verified) but fix the
// proj store regression via LDS TRANSPOSE in the epilogue.
// R16 post-mortem: direct transposed stores = 8B/lane at 16KB stride -> 64
// cache lines per store instr, WRITE_SIZE 49->76 GB*KB (1.6x amplification),
// proj 55.9->75.1us, MfmaUtil 39.7->28.2. Fix: stage the 128x128 tile in the
// 32KB LDS (dead after mainloop), barrier, write time-major rows coalesced
// (per wave-instr: 4 rows x 256B contiguous). Read side is at the wave64-b128
// bank floor on plain [128][128]; write-side 16-way aliasing ~200cyc/block.
// Arithmetic unchanged -> absmax must stay exactly .01953125.
// R15 lesson: no inter-block sync/fusion (XCD atomics serialize).
// R14 lesson: never shrink tail grids (latency-bound, need TLP).
// R13: rmsnorm deleted (row scalar folded into out_gemm epilogue via rowssq);
//   scanB = wave-per-channel Kogge-Stone.
// NOTE (R9): SQ_LDS_BANK_CONFLICT ~4/ds_read_b128 is structural; don't chase.
//
// ws (~42.6 MiB): x_c bf16 16M (scan output `so` reuses it) | W_c bf16 8M
//   (rowssq fp32 32K aliases Wr_c after proj) | v_t bf16 16M | ksum 512K |
//   wks 64K | Pbuf 1M | Abuf 1M.
// d_out scratch: r_t bf16 [0,16M), w_t bf16 [16M,32M).

#define BB 4
#define TT 2048
#define DD 1024
#define NHH 16
#define HDD 64
#define CC 64
#define LL 32
#define NCH 4096
#define MT (BB * TT)   // 8192 rows

using bf16 = __hip_bfloat16;
typedef __attribute__((ext_vector_type(8))) short bfrag8;
typedef __attribute__((ext_vector_type(8))) unsigned short us8;
typedef __attribute__((ext_vector_type(4))) float f32x4;

__device__ __forceinline__ void async_ld16(const bf16* g, bf16* l) {
  __builtin_amdgcn_global_load_lds(
      (const __attribute__((address_space(1))) uint32_t*)g,
      (__attribute__((address_space(3))) uint32_t*)l, 16, 0, 0);
}

__device__ __forceinline__ float sigm(float x) {
  // fast: v_exp_f32 + v_rcp_f32 (~1 ulp each; bf16 rounding downstream dominates)
  return __builtin_amdgcn_rcpf(1.0f + __expf(-x));
}
__device__ __forceinline__ float bf2f(bf16 h) {
  unsigned short u = *reinterpret_cast<unsigned short*>(&h);
  return __uint_as_float((unsigned)u << 16);
}
__device__ __forceinline__ float us2f(unsigned short u) {
  return __uint_as_float((unsigned)u << 16);
}
__device__ __forceinline__ unsigned short f2bfbits(float f) {
  bf16 b = __float2bfloat16(f);
  return *reinterpret_cast<unsigned short*>(&b);
}

// ---- fp32 -> bf16 convert (x + Wr,Wv,Ww,Wo) fused with wksum ----
// blocks [0,12288): convert; blocks [12288,12352): wks[h][c]=sum_j Wk[h*64+j][c]
__global__ __launch_bounds__(256)
void convert_kernel(const float* __restrict__ x,
                    const float* __restrict__ Wr, const float* __restrict__ Wv,
                    const float* __restrict__ Ww, const float* __restrict__ Wo,
                    const float* __restrict__ Wk,
                    bf16* __restrict__ x_c, bf16* __restrict__ W_c,
                    float* __restrict__ wks)
{
  if (blockIdx.x >= 12288) {
    const int gid = (blockIdx.x - 12288) * 256 + threadIdx.x;   // 16384
    const int h = gid >> 10, c = gid & 1023;
    float s = 0.0f;
    for (int j = 0; j < 64; ++j)
      s += Wk[(long)((h << 6) + j) * 1024 + c];
    wks[gid] = s;
    return;
  }
  const long g = (long)blockIdx.x * 256 + threadIdx.x;
  const float* src; bf16* dst; long off4;
  if (g < 2097152) { src = x; dst = x_c; off4 = g; }
  else {
    long gg = g - 2097152;
    int wsel = (int)(gg >> 18);
    off4 = gg & 262143;
    src = (wsel == 0) ? Wr : (wsel == 1) ? Wv : (wsel == 2) ? Ww : Wo;
    dst = W_c + (long)wsel * 1048576;
  }
  float4 f = reinterpret_cast<const float4*>(src)[off4];
  ushort4 pk;
  pk.x = f2bfbits(f.x); pk.y = f2bfbits(f.y);
  pk.z = f2bfbits(f.z); pk.w = f2bfbits(f.w);
  reinterpret_cast<ushort4*>(dst)[off4] = pk;
}

// ---- MFMA GEMM mainloop, BK=64, XOR-chunk staging permutation ----
// LDS row-major [128][64] bf16 (8 chunks of 16B per row).
// Staging: lane l (of a wave issue) covers row (l>>3), phys chunk (l&7),
// fetching GLOBAL chunk (l&7)^((l>>3)&7). Reads fetch phys (kh*4+quad)^(lane15&7).
__device__ __forceinline__ void gemm_mainloop(
    const bf16* __restrict__ A, const bf16* __restrict__ W,
    int blockM, int blockN, bf16* a_sh, bf16* b_sh, f32x4 acc[4][4])
{
  const int tid    = threadIdx.x;
  const int wave   = tid >> 6;
  const int lane   = tid & 63;
  const int lane15 = lane & 15;
  const int quad   = lane >> 4;
  const int waveM  = wave >> 1;
  const int waveN  = wave & 1;
  const int s_row  = (wave << 5) + (lane >> 3);                 // +it*8 below
  const int s_col  = (((lane & 7) ^ ((lane >> 3) & 7)) << 3);   // permuted global chunk

  const bf16* gA = A + ((long)(blockM * 128) + s_row) * 1024 + s_col;
  const bf16* gW = W + ((long)(blockN * 128) + s_row) * 1024 + s_col;
  bf16* la = a_sh + wave * 2048;   // 32 rows x 64 elems per wave
  bf16* lb = b_sh + wave * 2048;

  const int rsw = lane15 & 7;      // read-side xor key (= local row & 7)

  for (int k0 = 0; k0 < 1024; k0 += 64) {
#pragma unroll
    for (int it = 0; it < 4; ++it) {
      async_ld16(gA + k0 + it * 8 * 1024, la + it * 512);
      async_ld16(gW + k0 + it * 8 * 1024, lb + it * 512);
    }
    __syncthreads();
#pragma unroll
    for (int kh = 0; kh < 2; ++kh) {
      bfrag8 af[4], bfv[4];
      const int pc = ((kh * 4 + quad) ^ rsw) << 3;   // phys chunk elem offset
#pragma unroll
      for (int mi = 0; mi < 4; ++mi)
        af[mi] = *reinterpret_cast<const bfrag8*>(a_sh + (waveM*64 + mi*16 + lane15)*64 + pc);
#pragma unroll
      for (int ni = 0; ni < 4; ++ni)
        bfv[ni] = *reinterpret_cast<const bfrag8*>(b_sh + (waveN*64 + ni*16 + lane15)*64 + pc);
#pragma unroll
      for (int mi = 0; mi < 4; ++mi)
#pragma unroll
        for (int ni = 0; ni < 4; ++ni)
          acc[mi][ni] = __builtin_amdgcn_mfma_f32_16x16x32_bf16(af[mi], bfv[ni], acc[mi][ni], 0, 0, 0);
    }
    __syncthreads();
  }
}

// mode 0: r = sigm(x Wr^T)   1: v = x Wv^T   2: w = sigm(x Ww^T)*0.99
// 1-D grid 1536, XCD-pinned: f = m%8 + 8*(n + 8*(mh + 8*mode)).
// Epilogue: LDS-transpose (sh reused, 32KB = [128][128] bf16), then coalesced
// time-major stores arr_t[nn][mm]: per pass, 16 lanes cover one 256B row run.
__global__ __launch_bounds__(256, 2)
void proj_kernel(const bf16* __restrict__ X, const bf16* __restrict__ W_c,
                 bf16* __restrict__ r_t, bf16* __restrict__ v_t,
                 bf16* __restrict__ w_t)
{
  __shared__ __align__(16) bf16 sh[128 * 128];   // 32 KB: a=sh, b=sh+8192; reused as [nn][mm]
  const int f  = blockIdx.x;
  const int u  = f & 7;
  const int q  = f >> 3;
  const int n  = q & 7;
  const int p  = q >> 3;
  const int mh = p & 7;
  const int mode = p >> 3;
  const int m  = u + (mh << 3);

  const bf16* W = W_c + (long)mode * 1048576;
  f32x4 acc[4][4] = {};
  gemm_mainloop(X, W, m, n, sh, sh + 8192, acc);

  const int tid = threadIdx.x;
  const int wave = tid >> 6, lane = tid & 63;
  const int lane15 = lane & 15, quad = lane >> 4;
  const int waveM = wave >> 1, waveN = wave & 1;
  bf16* outp = (mode == 0) ? r_t : (mode == 1) ? v_t : w_t;

  // stage transposed tile: sh[nn_l][mm_l] (quadrants disjoint per wave)
  // (mainloop ended with __syncthreads -> safe to overwrite)
#pragma unroll
  for (int mi = 0; mi < 4; ++mi) {
    const int mm0 = waveM*64 + mi*16 + quad*4;
#pragma unroll
    for (int ni = 0; ni < 4; ++ni) {
      const int nn = waveN*64 + ni*16 + lane15;
      float v0 = acc[mi][ni][0], v1 = acc[mi][ni][1];
      float v2 = acc[mi][ni][2], v3 = acc[mi][ni][3];
      if (mode == 0) { v0 = sigm(v0); v1 = sigm(v1); v2 = sigm(v2); v3 = sigm(v3); }
      else if (mode == 2) {
        v0 = sigm(v0)*0.99f; v1 = sigm(v1)*0.99f;
        v2 = sigm(v2)*0.99f; v3 = sigm(v3)*0.99f;
      }
      ushort4 pk;
      pk.x = f2bfbits(v0); pk.y = f2bfbits(v1);
      pk.z = f2bfbits(v2); pk.w = f2bfbits(v3);
      *reinterpret_cast<ushort4*>(sh + nn*128 + mm0) = pk;
    }
  }
  __syncthreads();

  // coalesced time-major write-out: pass pp -> rows pp*16+(tid>>4),
  // 16 lanes x us8 cover the row's 128 mm (256B contiguous per row).
  const int nn_base = n * 128;
  const int mm_base = m * 128;
#pragma unroll
  for (int pp = 0; pp < 8; ++pp) {
    const int nn_l = pp*16 + (tid >> 4);
    const int mm_l = (tid & 15) * 8;
    us8 v = *reinterpret_cast<const us8*>(sh + nn_l*128 + mm_l);
    *reinterpret_cast<us8*>(outp + (long)(nn_base + nn_l) * MT + (mm_base + mm_l)) = v;
  }
}

// ---- ksum[b,h,t] = x_row(m) . wks[h]  (R13-verified form) ----
__global__ __launch_bounds__(256)
void ksum_kernel(const bf16* __restrict__ X, const float* __restrict__ wks,
                 float* __restrict__ ksum)
{
  __shared__ __align__(8) bf16 xs[DD];
  const int m = blockIdx.x;
  const int tid = threadIdx.x;
  *reinterpret_cast<ushort4*>(xs + tid*4) =
      *reinterpret_cast<const ushort4*>(X + (long)m * DD + tid*4);
  __syncthreads();
  const int wave = tid >> 6, lane = tid & 63;
  const int b = m >> 11, t = m & (TT - 1);
#pragma unroll
  for (int hi = 0; hi < 4; ++hi) {
    const int h = wave * 4 + hi;
    float acc = 0.0f;
#pragma unroll
    for (int i = 0; i < 16; ++i) {
      const int c = lane + (i << 6);
      acc += bf2f(xs[c]) * wks[h * DD + c];
    }
#pragma unroll
    for (int msk = 1; msk <= 32; msk <<= 1) acc += __shfl_xor(acc, msk);
    if (lane == 0) ksum[((long)(b * NHH + h)) * TT + t] = acc;
  }
}

// ---- scan A (time-major): per (channel, chunk): P = prod w, A = local scan ----
// grid (64,16) x 256 as R13. Thread (cg,i): channel ch=h*64+i, chunk yb*4+cg.
// Loads: 4x us8 (16B) per array, j contiguous -> MLP-saturated.
__global__ __launch_bounds__(256)
void scanA_kernel(const bf16* __restrict__ v_t, const bf16* __restrict__ w_t,
                  const float* __restrict__ ksum,
                  float* __restrict__ Pbuf, float* __restrict__ Abuf)
{
  __shared__ float ks_sh[128];
  const int bh = blockIdx.x;
  const int b = bh >> 4, h = bh & 15;
  const int tid = threadIdx.x;
  const int i = tid & 63;
  const int cg = tid >> 6;
  const int chunk = blockIdx.y * 4 + cg;
  if (tid < 128) ks_sh[tid] = ksum[(long)bh * TT + blockIdx.y * 128 + tid];
  __syncthreads();
  const int ch = h * HDD + i;
  const long tbase = (long)ch * MT + b * TT + chunk * LL;
  us8 wv[4], vv[4];
#pragma unroll
  for (int q = 0; q < 4; ++q) {
    wv[q] = *reinterpret_cast<const us8*>(w_t + tbase + q*8);
    vv[q] = *reinterpret_cast<const us8*>(v_t + tbase + q*8);
  }
  const float* ksp = ks_sh + cg * LL;
  float s = 0.0f, P = 1.0f;
#pragma unroll
  for (int j = 0; j < LL; ++j) {
    float wf = us2f((unsigned short)wv[j>>3][j&7]);
    float vf = us2f((unsigned short)vv[j>>3][j&7]);
    s = fmaf(wf, s, vf * ksp[j]);
    P *= wf;
  }
  const int chn = bh * 64 + i;
  Pbuf[chunk * NCH + chn] = P;
  Abuf[chunk * NCH + chn] = s;
}

// ---- scan B: wave-per-channel Kogge-Stone over 64 chunk carries.
// grid 1024 x 256: wave w of block handles channel blockIdx.x*4 + w; lane=chunk.
// Also zeroes rowssq (kernel boundary orders it before scanC's atomics).
__global__ __launch_bounds__(256)
void scanB_kernel(const float* __restrict__ Pbuf, float* __restrict__ Abuf,
                  float* __restrict__ rowssq)
{
  const int tid  = threadIdx.x;
  const int lane = tid & 63;                       // = chunk index
  const int wch  = blockIdx.x * 4 + (tid >> 6);    // channel 0..4095
  const int idx  = lane * NCH + wch;
  float p = Pbuf[idx];
  float a = Abuf[idx];
#pragma unroll
  for (int d = 1; d < 64; d <<= 1) {
    float al = __shfl_up(a, d);
    float pl = __shfl_up(p, d);
    if (lane >= d) { a = fmaf(p, al, a); p *= pl; }
  }
  float carry = __shfl_up(a, 1);                   // exclusive prefix
  if (lane == 0) carry = 0.0f;
  Abuf[idx] = carry;                               // column owned by this wave
  if (blockIdx.x < 32) rowssq[blockIdx.x * 256 + tid] = 0.0f;   // 8192 floats
}

// ---- scan C (time-major inputs): re-scan from carry; out = r*s into
//      so[m][d] (row-major for out_gemm); per-row ssq -> rowssq atomics. ----
__global__ __launch_bounds__(256)
void scanC_kernel(const bf16* __restrict__ r_t, const bf16* __restrict__ v_t,
                  const bf16* __restrict__ w_t, const float* __restrict__ ksum,
                  const float* __restrict__ Abuf, bf16* __restrict__ so,
                  float* __restrict__ rowssq)
{
  __shared__ float ks_sh[128];
  const int bh = blockIdx.x;
  const int b = bh >> 4, h = bh & 15;
  const int tid = threadIdx.x;
  const int i = tid & 63;
  const int cg = tid >> 6;
  const int chunk = blockIdx.y * 4 + cg;
  if (tid < 128) ks_sh[tid] = ksum[(long)bh * TT + blockIdx.y * 128 + tid];
  __syncthreads();
  const int ch = h * HDD + i;
  const long tbase = (long)ch * MT + b * TT + chunk * LL;
  us8 wv[4], vv[4], rv[4];
#pragma unroll
  for (int q = 0; q < 4; ++q) {
    wv[q] = *reinterpret_cast<const us8*>(w_t + tbase + q*8);
    vv[q] = *reinterpret_cast<const us8*>(v_t + tbase + q*8);
    rv[q] = *reinterpret_cast<const us8*>(r_t + tbase + q*8);
  }
  const float* ksp = ks_sh + cg * LL;
  const int chn = bh * 64 + i;
  float s = Abuf[chunk * NCH + chn];
  const long obase = (long)(b * TT + chunk * LL) * DD + ch;
#pragma unroll
  for (int j = 0; j < LL; ++j) {
    float wf = us2f((unsigned short)wv[j>>3][j&7]);
    float vf = us2f((unsigned short)vv[j>>3][j&7]);
    float rf = us2f((unsigned short)rv[j>>3][j&7]);
    s = fmaf(wf, s, vf * ksp[j]);
    unsigned short ob = f2bfbits(rf * s);
    *reinterpret_cast<unsigned short*>(so + obase + (long)j * DD) = ob;
    // ssq of the exact bf16-rounded stored value (matches old rmsnorm input)
    float vfo = us2f(ob);
    float ss = vfo * vfo;
#pragma unroll
    for (int msk = 1; msk <= 32; msk <<= 1) ss += __shfl_xor(ss, msk);
    if (i == 0) atomicAdd(&rowssq[b * TT + chunk * LL + j], ss);
  }
}

// ---- out = so @ Wo^T scaled by per-row rsqrt(mean sq), fp32 stores. ----
// 1-D grid 512, XCD-pinned. RMSNorm fused: out[m,:] = scale[m]*(A[m,:] Wo^T).
__global__ __launch_bounds__(256, 2)
void out_gemm_kernel(const bf16* __restrict__ A, const bf16* __restrict__ Wo_c,
                     const float* __restrict__ rowssq, float* __restrict__ out)
{
  __shared__ __align__(16) bf16 a_sh[128*64];
  __shared__ __align__(16) bf16 b_sh[128*64];
  const int f  = blockIdx.x;
  const int u  = f & 7;
  const int q  = f >> 3;
  const int n  = q & 7;
  const int mh = q >> 3;
  const int m  = u + (mh << 3);

  f32x4 acc[4][4] = {};
  gemm_mainloop(A, Wo_c, m, n, a_sh, b_sh, acc);

  const int tid = threadIdx.x;
  const int wave = tid >> 6, lane = tid & 63;
  const int lane15 = lane & 15, quad = lane >> 4;
  const int waveM = wave >> 1, waveN = wave & 1;
  const int m_base = m * 128 + waveM * 64;
  const int n_base = n * 128 + waveN * 64;
#pragma unroll
  for (int mi = 0; mi < 4; ++mi)
#pragma unroll
    for (int r = 0; r < 4; ++r) {
      int mm = m_base + mi*16 + quad*4 + r;
      float sc = rsqrtf(rowssq[mm] * (1.0f / DD) + 1.1920929e-07f);
#pragma unroll
      for (int ni = 0; ni < 4; ++ni) {
        int nn = n_base + ni*16 + lane15;
        out[(long)mm * DD + nn] = acc[mi][ni][r] * sc;
      }
    }
}

extern "C" void kernel_launch(void* const* d_in, const int* in_sizes, int n_in,
                              void* d_out, int out_size, void* d_ws, size_t ws_size,
                              hipStream_t stream) {
  const float* x  = (const float*)d_in[0];
  const float* Wr = (const float*)d_in[1];
  const float* Wk = (const float*)d_in[2];
  const float* Wv = (const float*)d_in[3];
  const float* Ww = (const float*)d_in[4];
  const float* Wo = (const float*)d_in[5];

  const long NELT = (long)BB * TT * DD;            // 8388608
  bf16*  x_c  = (bf16*)d_ws;                       // 16 MiB (scan output reuses)
  bf16*  W_c  = x_c + NELT;                        // 8 MiB
  bf16*  v_t  = W_c + 4 * 1048576;                 // 16 MiB (time-major v)
  float* ksum = (float*)(v_t + NELT);              // 512 KiB
  float* wks  = ksum + (long)BB * NHH * TT;        // 64 KiB
  float* Pbuf = wks + NHH * DD;                    // 1 MiB
  float* Abuf = Pbuf + (long)CC * NCH;             // 1 MiB
  float* rowssq = (float*)W_c;                     // 32 KiB, aliases Wr_c (dead after proj)

  bf16*  r_t  = (bf16*)d_out;                      // d_out scratch (time-major)
  bf16*  w_t  = (bf16*)d_out + NELT;
  bf16*  so   = x_c;                               // scan output [m][d] (x_c dead after ksum)
  float* out  = (float*)d_out;

  convert_kernel<<<dim3(12352), 256, 0, stream>>>(x, Wr, Wv, Ww, Wo, Wk, x_c, W_c, wks);
  proj_kernel<<<dim3(1536), 256, 0, stream>>>(x_c, W_c, r_t, v_t, w_t);
  ksum_kernel<<<dim3(BB * TT), 256, 0, stream>>>(x_c, wks, ksum);
  scanA_kernel<<<dim3(64, 16), 256, 0, stream>>>(v_t, w_t, ksum, Pbuf, Abuf);
  scanB_kernel<<<dim3(1024), 256, 0, stream>>>(Pbuf, Abuf, rowssq);
  scanC_kernel<<<dim3(64, 16), 256, 0, stream>>>(r_t, v_t, w_t, ksum, Abuf, so, rowssq);
  out_gemm_kernel<<<dim3(512), 256, 0, stream>>>(so, W_c + 3 * 1048576, rowssq, out);
}

// Round 8
// 239.624 us; speedup vs baseline: 1.0752x; 1.0752x over previous
//
#include <hip/hip_runtime.h>
#include <hip/hip_bf16.h>
#include <stdint.h>

// RWKV7-like block: B=4 T=2048 D=1024 NH=16 HD=64.
// Inputs fp32 (order x,Wr,Wk,Wv,Ww,Wo); OUTPUT FP32. Verified R7-R9,R13,R16,R17 (absmax .0195).
//
// R18: fix R17's LDS-transpose bank conflicts with +8-elem row pad.
// R17 post-mortem: WRITE amplification fixed (49152 ✓) but transpose LDS was
// [128][128]: stage writes had bank=(64*nn)%32=const -> 16-way conflict;
// read-out groups aliased one bank set. SQ_LDS_BANK_CONFLICT 5.9M, proj 63.3us.
// Fix: sh[128][136] bf16 (row stride 272B = 68 dwords -> bank rotation 4/row):
// stage writes land 2 lanes/bank (wave64 free minimum, m136); read-out = same
// class as mainloop's 0-conflict ds_read_b128; 16B alignment kept (272=17*16).
// LDS 34816B, still 2 blocks/CU. Single-variable change vs R17.
// NOTE: R17 e2e (257.6) inconsistent with its own per-dispatch deltas (proj
// -11.8 vs R16, tail identical); treating as session clock variance. If R18
// proj ~58us but e2e >=250, switch objective to summed dispatch durs.
// R16: time-major r/v/w (scans MLP-saturated); direct transposed stores were
//   the mistake (64 lines/store-instr), hence LDS transpose.
// R15 lesson: no inter-block sync/fusion (XCD atomics serialize).
// R14 lesson: never shrink tail grids (latency-bound, need TLP).
// R13: rmsnorm deleted (row scalar folded into out_gemm epilogue via rowssq);
//   scanB = wave-per-channel Kogge-Stone.
// NOTE (R9): SQ_LDS_BANK_CONFLICT ~4/ds_read_b128 is structural; don't chase.
//
// ws (~42.6 MiB): x_c bf16 16M (scan output `so` reuses it) | W_c bf16 8M
//   (rowssq fp32 32K aliases Wr_c after proj) | v_t bf16 16M | ksum 512K |
//   wks 64K | Pbuf 1M | Abuf 1M.
// d_out scratch: r_t bf16 [0,16M), w_t bf16 [16M,32M).

#define BB 4
#define TT 2048
#define DD 1024
#define NHH 16
#define HDD 64
#define CC 64
#define LL 32
#define NCH 4096
#define MT (BB * TT)   // 8192 rows
#define ROWP 136       // padded LDS row stride (bf16 elems) for the transpose

using bf16 = __hip_bfloat16;
typedef __attribute__((ext_vector_type(8))) short bfrag8;
typedef __attribute__((ext_vector_type(8))) unsigned short us8;
typedef __attribute__((ext_vector_type(4))) float f32x4;

__device__ __forceinline__ void async_ld16(const bf16* g, bf16* l) {
  __builtin_amdgcn_global_load_lds(
      (const __attribute__((address_space(1))) uint32_t*)g,
      (__attribute__((address_space(3))) uint32_t*)l, 16, 0, 0);
}

__device__ __forceinline__ float sigm(float x) {
  // fast: v_exp_f32 + v_rcp_f32 (~1 ulp each; bf16 rounding downstream dominates)
  return __builtin_amdgcn_rcpf(1.0f + __expf(-x));
}
__device__ __forceinline__ float bf2f(bf16 h) {
  unsigned short u = *reinterpret_cast<unsigned short*>(&h);
  return __uint_as_float((unsigned)u << 16);
}
__device__ __forceinline__ float us2f(unsigned short u) {
  return __uint_as_float((unsigned)u << 16);
}
__device__ __forceinline__ unsigned short f2bfbits(float f) {
  bf16 b = __float2bfloat16(f);
  return *reinterpret_cast<unsigned short*>(&b);
}

// ---- fp32 -> bf16 convert (x + Wr,Wv,Ww,Wo) fused with wksum ----
// blocks [0,12288): convert; blocks [12288,12352): wks[h][c]=sum_j Wk[h*64+j][c]
__global__ __launch_bounds__(256)
void convert_kernel(const float* __restrict__ x,
                    const float* __restrict__ Wr, const float* __restrict__ Wv,
                    const float* __restrict__ Ww, const float* __restrict__ Wo,
                    const float* __restrict__ Wk,
                    bf16* __restrict__ x_c, bf16* __restrict__ W_c,
                    float* __restrict__ wks)
{
  if (blockIdx.x >= 12288) {
    const int gid = (blockIdx.x - 12288) * 256 + threadIdx.x;   // 16384
    const int h = gid >> 10, c = gid & 1023;
    float s = 0.0f;
    for (int j = 0; j < 64; ++j)
      s += Wk[(long)((h << 6) + j) * 1024 + c];
    wks[gid] = s;
    return;
  }
  const long g = (long)blockIdx.x * 256 + threadIdx.x;
  const float* src; bf16* dst; long off4;
  if (g < 2097152) { src = x; dst = x_c; off4 = g; }
  else {
    long gg = g - 2097152;
    int wsel = (int)(gg >> 18);
    off4 = gg & 262143;
    src = (wsel == 0) ? Wr : (wsel == 1) ? Wv : (wsel == 2) ? Ww : Wo;
    dst = W_c + (long)wsel * 1048576;
  }
  float4 f = reinterpret_cast<const float4*>(src)[off4];
  ushort4 pk;
  pk.x = f2bfbits(f.x); pk.y = f2bfbits(f.y);
  pk.z = f2bfbits(f.z); pk.w = f2bfbits(f.w);
  reinterpret_cast<ushort4*>(dst)[off4] = pk;
}

// ---- MFMA GEMM mainloop, BK=64, XOR-chunk staging permutation ----
// LDS row-major [128][64] bf16 (8 chunks of 16B per row).
// Staging: lane l (of a wave issue) covers row (l>>3), phys chunk (l&7),
// fetching GLOBAL chunk (l&7)^((l>>3)&7). Reads fetch phys (kh*4+quad)^(lane15&7).
__device__ __forceinline__ void gemm_mainloop(
    const bf16* __restrict__ A, const bf16* __restrict__ W,
    int blockM, int blockN, bf16* a_sh, bf16* b_sh, f32x4 acc[4][4])
{
  const int tid    = threadIdx.x;
  const int wave   = tid >> 6;
  const int lane   = tid & 63;
  const int lane15 = lane & 15;
  const int quad   = lane >> 4;
  const int waveM  = wave >> 1;
  const int waveN  = wave & 1;
  const int s_row  = (wave << 5) + (lane >> 3);                 // +it*8 below
  const int s_col  = (((lane & 7) ^ ((lane >> 3) & 7)) << 3);   // permuted global chunk

  const bf16* gA = A + ((long)(blockM * 128) + s_row) * 1024 + s_col;
  const bf16* gW = W + ((long)(blockN * 128) + s_row) * 1024 + s_col;
  bf16* la = a_sh + wave * 2048;   // 32 rows x 64 elems per wave
  bf16* lb = b_sh + wave * 2048;

  const int rsw = lane15 & 7;      // read-side xor key (= local row & 7)

  for (int k0 = 0; k0 < 1024; k0 += 64) {
#pragma unroll
    for (int it = 0; it < 4; ++it) {
      async_ld16(gA + k0 + it * 8 * 1024, la + it * 512);
      async_ld16(gW + k0 + it * 8 * 1024, lb + it * 512);
    }
    __syncthreads();
#pragma unroll
    for (int kh = 0; kh < 2; ++kh) {
      bfrag8 af[4], bfv[4];
      const int pc = ((kh * 4 + quad) ^ rsw) << 3;   // phys chunk elem offset
#pragma unroll
      for (int mi = 0; mi < 4; ++mi)
        af[mi] = *reinterpret_cast<const bfrag8*>(a_sh + (waveM*64 + mi*16 + lane15)*64 + pc);
#pragma unroll
      for (int ni = 0; ni < 4; ++ni)
        bfv[ni] = *reinterpret_cast<const bfrag8*>(b_sh + (waveN*64 + ni*16 + lane15)*64 + pc);
#pragma unroll
      for (int mi = 0; mi < 4; ++mi)
#pragma unroll
        for (int ni = 0; ni < 4; ++ni)
          acc[mi][ni] = __builtin_amdgcn_mfma_f32_16x16x32_bf16(af[mi], bfv[ni], acc[mi][ni], 0, 0, 0);
    }
    __syncthreads();
  }
}

// mode 0: r = sigm(x Wr^T)   1: v = x Wv^T   2: w = sigm(x Ww^T)*0.99
// 1-D grid 1536, XCD-pinned: f = m%8 + 8*(n + 8*(mh + 8*mode)).
// Epilogue: LDS-transpose into padded [128][ROWP=136] (bank rotation 4/row:
// stage writes 2 lanes/bank = free; read-out = mainloop-class b128 pattern),
// then coalesced time-major stores (4 rows x 256B contiguous per wave-instr).
__global__ __launch_bounds__(256, 2)
void proj_kernel(const bf16* __restrict__ X, const bf16* __restrict__ W_c,
                 bf16* __restrict__ r_t, bf16* __restrict__ v_t,
                 bf16* __restrict__ w_t)
{
  __shared__ __align__(16) bf16 sh[128 * ROWP];  // 34816B; mainloop uses first 32KB
  const int f  = blockIdx.x;
  const int u  = f & 7;
  const int q  = f >> 3;
  const int n  = q & 7;
  const int p  = q >> 3;
  const int mh = p & 7;
  const int mode = p >> 3;
  const int m  = u + (mh << 3);

  const bf16* W = W_c + (long)mode * 1048576;
  f32x4 acc[4][4] = {};
  gemm_mainloop(X, W, m, n, sh, sh + 8192, acc);

  const int tid = threadIdx.x;
  const int wave = tid >> 6, lane = tid & 63;
  const int lane15 = lane & 15, quad = lane >> 4;
  const int waveM = wave >> 1, waveN = wave & 1;
  bf16* outp = (mode == 0) ? r_t : (mode == 1) ? v_t : w_t;

  // stage transposed tile: sh[nn_l][mm_l] with padded stride (quadrants
  // disjoint per wave; mainloop ended with __syncthreads -> safe to overwrite)
#pragma unroll
  for (int mi = 0; mi < 4; ++mi) {
    const int mm0 = waveM*64 + mi*16 + quad*4;
#pragma unroll
    for (int ni = 0; ni < 4; ++ni) {
      const int nn = waveN*64 + ni*16 + lane15;
      float v0 = acc[mi][ni][0], v1 = acc[mi][ni][1];
      float v2 = acc[mi][ni][2], v3 = acc[mi][ni][3];
      if (mode == 0) { v0 = sigm(v0); v1 = sigm(v1); v2 = sigm(v2); v3 = sigm(v3); }
      else if (mode == 2) {
        v0 = sigm(v0)*0.99f; v1 = sigm(v1)*0.99f;
        v2 = sigm(v2)*0.99f; v3 = sigm(v3)*0.99f;
      }
      ushort4 pk;
      pk.x = f2bfbits(v0); pk.y = f2bfbits(v1);
      pk.z = f2bfbits(v2); pk.w = f2bfbits(v3);
      *reinterpret_cast<ushort4*>(sh + nn*ROWP + mm0) = pk;
    }
  }
  __syncthreads();

  // coalesced time-major write-out: pass pp -> rows pp*16+(tid>>4),
  // 16 lanes x us8 cover the row's 128 mm (256B contiguous per row).
  const int nn_base = n * 128;
  const int mm_base = m * 128;
#pragma unroll
  for (int pp = 0; pp < 8; ++pp) {
    const int nn_l = pp*16 + (tid >> 4);
    const int mm_l = (tid & 15) * 8;
    us8 v = *reinterpret_cast<const us8*>(sh + nn_l*ROWP + mm_l);
    *reinterpret_cast<us8*>(outp + (long)(nn_base + nn_l) * MT + (mm_base + mm_l)) = v;
  }
}

// ---- ksum[b,h,t] = x_row(m) . wks[h]  (R13-verified form) ----
__global__ __launch_bounds__(256)
void ksum_kernel(const bf16* __restrict__ X, const float* __restrict__ wks,
                 float* __restrict__ ksum)
{
  __shared__ __align__(8) bf16 xs[DD];
  const int m = blockIdx.x;
  const int tid = threadIdx.x;
  *reinterpret_cast<ushort4*>(xs + tid*4) =
      *reinterpret_cast<const ushort4*>(X + (long)m * DD + tid*4);
  __syncthreads();
  const int wave = tid >> 6, lane = tid & 63;
  const int b = m >> 11, t = m & (TT - 1);
#pragma unroll
  for (int hi = 0; hi < 4; ++hi) {
    const int h = wave * 4 + hi;
    float acc = 0.0f;
#pragma unroll
    for (int i = 0; i < 16; ++i) {
      const int c = lane + (i << 6);
      acc += bf2f(xs[c]) * wks[h * DD + c];
    }
#pragma unroll
    for (int msk = 1; msk <= 32; msk <<= 1) acc += __shfl_xor(acc, msk);
    if (lane == 0) ksum[((long)(b * NHH + h)) * TT + t] = acc;
  }
}

// ---- scan A (time-major): per (channel, chunk): P = prod w, A = local scan ----
// grid (64,16) x 256 as R13. Thread (cg,i): channel ch=h*64+i, chunk yb*4+cg.
// Loads: 4x us8 (16B) per array, j contiguous -> MLP-saturated.
__global__ __launch_bounds__(256)
void scanA_kernel(const bf16* __restrict__ v_t, const bf16* __restrict__ w_t,
                  const float* __restrict__ ksum,
                  float* __restrict__ Pbuf, float* __restrict__ Abuf)
{
  __shared__ float ks_sh[128];
  const int bh = blockIdx.x;
  const int b = bh >> 4, h = bh & 15;
  const int tid = threadIdx.x;
  const int i = tid & 63;
  const int cg = tid >> 6;
  const int chunk = blockIdx.y * 4 + cg;
  if (tid < 128) ks_sh[tid] = ksum[(long)bh * TT + blockIdx.y * 128 + tid];
  __syncthreads();
  const int ch = h * HDD + i;
  const long tbase = (long)ch * MT + b * TT + chunk * LL;
  us8 wv[4], vv[4];
#pragma unroll
  for (int q = 0; q < 4; ++q) {
    wv[q] = *reinterpret_cast<const us8*>(w_t + tbase + q*8);
    vv[q] = *reinterpret_cast<const us8*>(v_t + tbase + q*8);
  }
  const float* ksp = ks_sh + cg * LL;
  float s = 0.0f, P = 1.0f;
#pragma unroll
  for (int j = 0; j < LL; ++j) {
    float wf = us2f((unsigned short)wv[j>>3][j&7]);
    float vf = us2f((unsigned short)vv[j>>3][j&7]);
    s = fmaf(wf, s, vf * ksp[j]);
    P *= wf;
  }
  const int chn = bh * 64 + i;
  Pbuf[chunk * NCH + chn] = P;
  Abuf[chunk * NCH + chn] = s;
}

// ---- scan B: wave-per-channel Kogge-Stone over 64 chunk carries.
// grid 1024 x 256: wave w of block handles channel blockIdx.x*4 + w; lane=chunk.
// Also zeroes rowssq (kernel boundary orders it before scanC's atomics).
__global__ __launch_bounds__(256)
void scanB_kernel(const float* __restrict__ Pbuf, float* __restrict__ Abuf,
                  float* __restrict__ rowssq)
{
  const int tid  = threadIdx.x;
  const int lane = tid & 63;                       // = chunk index
  const int wch  = blockIdx.x * 4 + (tid >> 6);    // channel 0..4095
  const int idx  = lane * NCH + wch;
  float p = Pbuf[idx];
  float a = Abuf[idx];
#pragma unroll
  for (int d = 1; d < 64; d <<= 1) {
    float al = __shfl_up(a, d);
    float pl = __shfl_up(p, d);
    if (lane >= d) { a = fmaf(p, al, a); p *= pl; }
  }
  float carry = __shfl_up(a, 1);                   // exclusive prefix
  if (lane == 0) carry = 0.0f;
  Abuf[idx] = carry;                               // column owned by this wave
  if (blockIdx.x < 32) rowssq[blockIdx.x * 256 + tid] = 0.0f;   // 8192 floats
}

// ---- scan C (time-major inputs): re-scan from carry; out = r*s into
//      so[m][d] (row-major for out_gemm); per-row ssq -> rowssq atomics. ----
__global__ __launch_bounds__(256)
void scanC_kernel(const bf16* __restrict__ r_t, const bf16* __restrict__ v_t,
                  const bf16* __restrict__ w_t, const float* __restrict__ ksum,
                  const float* __restrict__ Abuf, bf16* __restrict__ so,
                  float* __restrict__ rowssq)
{
  __shared__ float ks_sh[128];
  const int bh = blockIdx.x;
  const int b = bh >> 4, h = bh & 15;
  const int tid = threadIdx.x;
  const int i = tid & 63;
  const int cg = tid >> 6;
  const int chunk = blockIdx.y * 4 + cg;
  if (tid < 128) ks_sh[tid] = ksum[(long)bh * TT + blockIdx.y * 128 + tid];
  __syncthreads();
  const int ch = h * HDD + i;
  const long tbase = (long)ch * MT + b * TT + chunk * LL;
  us8 wv[4], vv[4], rv[4];
#pragma unroll
  for (int q = 0; q < 4; ++q) {
    wv[q] = *reinterpret_cast<const us8*>(w_t + tbase + q*8);
    vv[q] = *reinterpret_cast<const us8*>(v_t + tbase + q*8);
    rv[q] = *reinterpret_cast<const us8*>(r_t + tbase + q*8);
  }
  const float* ksp = ks_sh + cg * LL;
  const int chn = bh * 64 + i;
  float s = Abuf[chunk * NCH + chn];
  const long obase = (long)(b * TT + chunk * LL) * DD + ch;
#pragma unroll
  for (int j = 0; j < LL; ++j) {
    float wf = us2f((unsigned short)wv[j>>3][j&7]);
    float vf = us2f((unsigned short)vv[j>>3][j&7]);
    float rf = us2f((unsigned short)rv[j>>3][j&7]);
    s = fmaf(wf, s, vf * ksp[j]);
    unsigned short ob = f2bfbits(rf * s);
    *reinterpret_cast<unsigned short*>(so + obase + (long)j * DD) = ob;
    // ssq of the exact bf16-rounded stored value (matches old rmsnorm input)
    float vfo = us2f(ob);
    float ss = vfo * vfo;
#pragma unroll
    for (int msk = 1; msk <= 32; msk <<= 1) ss += __shfl_xor(ss, msk);
    if (i == 0) atomicAdd(&rowssq[b * TT + chunk * LL + j], ss);
  }
}

// ---- out = so @ Wo^T scaled by per-row rsqrt(mean sq), fp32 stores. ----
// 1-D grid 512, XCD-pinned. RMSNorm fused: out[m,:] = scale[m]*(A[m,:] Wo^T).
__global__ __launch_bounds__(256, 2)
void out_gemm_kernel(const bf16* __restrict__ A, const bf16* __restrict__ Wo_c,
                     const float* __restrict__ rowssq, float* __restrict__ out)
{
  __shared__ __align__(16) bf16 a_sh[128*64];
  __shared__ __align__(16) bf16 b_sh[128*64];
  const int f  = blockIdx.x;
  const int u  = f & 7;
  const int q  = f >> 3;
  const int n  = q & 7;
  const int mh = q >> 3;
  const int m  = u + (mh << 3);

  f32x4 acc[4][4] = {};
  gemm_mainloop(A, Wo_c, m, n, a_sh, b_sh, acc);

  const int tid = threadIdx.x;
  const int wave = tid >> 6, lane = tid & 63;
  const int lane15 = lane & 15, quad = lane >> 4;
  const int waveM = wave >> 1, waveN = wave & 1;
  const int m_base = m * 128 + waveM * 64;
  const int n_base = n * 128 + waveN * 64;
#pragma unroll
  for (int mi = 0; mi < 4; ++mi)
#pragma unroll
    for (int r = 0; r < 4; ++r) {
      int mm = m_base + mi*16 + quad*4 + r;
      float sc = rsqrtf(rowssq[mm] * (1.0f / DD) + 1.1920929e-07f);
#pragma unroll
      for (int ni = 0; ni < 4; ++ni) {
        int nn = n_base + ni*16 + lane15;
        out[(long)mm * DD + nn] = acc[mi][ni][r] * sc;
      }
    }
}

extern "C" void kernel_launch(void* const* d_in, const int* in_sizes, int n_in,
                              void* d_out, int out_size, void* d_ws, size_t ws_size,
                              hipStream_t stream) {
  const float* x  = (const float*)d_in[0];
  const float* Wr = (const float*)d_in[1];
  const float* Wk = (const float*)d_in[2];
  const float* Wv = (const float*)d_in[3];
  const float* Ww = (const float*)d_in[4];
  const float* Wo = (const float*)d_in[5];

  const long NELT = (long)BB * TT * DD;            // 8388608
  bf16*  x_c  = (bf16*)d_ws;                       // 16 MiB (scan output reuses)
  bf16*  W_c  = x_c + NELT;                        // 8 MiB
  bf16*  v_t  = W_c + 4 * 1048576;                 // 16 MiB (time-major v)
  float* ksum = (float*)(v_t + NELT);              // 512 KiB
  float* wks  = ksum + (long)BB * NHH * TT;        // 64 KiB
  float* Pbuf = wks + NHH * DD;                    // 1 MiB
  float* Abuf = Pbuf + (long)CC * NCH;             // 1 MiB
  float* rowssq = (float*)W_c;                     // 32 KiB, aliases Wr_c (dead after proj)

  bf16*  r_t  = (bf16*)d_out;                      // d_out scratch (time-major)
  bf16*  w_t  = (bf16*)d_out + NELT;
  bf16*  so   = x_c;                               // scan output [m][d] (x_c dead after ksum)
  float* out  = (float*)d_out;

  convert_kernel<<<dim3(12352), 256, 0, stream>>>(x, Wr, Wv, Ww, Wo, Wk, x_c, W_c, wks);
  proj_kernel<<<dim3(1536), 256, 0, stream>>>(x_c, W_c, r_t, v_t, w_t);
  ksum_kernel<<<dim3(BB * TT), 256, 0, stream>>>(x_c, wks, ksum);
  scanA_kernel<<<dim3(64, 16), 256, 0, stream>>>(v_t, w_t, ksum, Pbuf, Abuf);
  scanB_kernel<<<dim3(1024), 256, 0, stream>>>(Pbuf, Abuf, rowssq);
  scanC_kernel<<<dim3(64, 16), 256, 0, stream>>>(r_t, v_t, w_t, ksum, Abuf, so, rowssq);
  out_gemm_kernel<<<dim3(512), 256, 0, stream>>>(so, W_c + 3 * 1048576, rowssq, out);
}

// Round 9
// 236.719 us; speedup vs baseline: 1.0884x; 1.0123x over previous
//
#include <hip/hip_runtime.h>
#include <hip/hip_bf16.h>
#include <stdint.h>

// RWKV7-like block: B=4 T=2048 D=1024 NH=16 HD=64.
// Inputs fp32 (order x,Wr,Wk,Wv,Ww,Wo); OUTPUT FP32. Verified thru R18 (absmax .0195).
//
// R19: merge ksum into proj as TAIL BLOCKS (grid 1536+8192=9728; blocks>=1536
// run the R13-verified ksum body, reusing proj's static LDS as xs). ksum and
// proj are independent (both consume only convert outputs); proj is compute-
// bound (MfmaUtil 39, HBM 22%) so ksum's 512MB L2 re-read (~15-20us alone)
// hides under proj's MFMA. Block-uniform branch (no divergent syncthreads);
// proj blocks keep ids 0..1535 -> XCD mapping untouched. 7 -> 6 launches.
// R18 (verified): +8-pad LDS transpose: proj 54.1us, conflicts 5.9M->590K,
//   WRITE 49152, MfmaUtil ~39. Cross-session e2e noise ±8-10us; per-dispatch
//   counters are the trustworthy signal.
// R16 (verified): time-major r/v/w -> scans MLP-saturated (us8 loads).
// R15 lesson: no inter-block sync/fusion (XCD atomics serialize).
// R14 lesson: never shrink tail grids (latency-bound, need TLP).
// R13: rmsnorm deleted (row scalar folded into out_gemm epilogue via rowssq);
//   scanB = wave-per-channel Kogge-Stone.
// NOTE (R9): SQ_LDS_BANK_CONFLICT ~4/ds_read_b128 is structural; don't chase.
//
// ws (~42.6 MiB): x_c bf16 16M (scan output `so` reuses it) | W_c bf16 8M
//   (rowssq fp32 32K aliases Wr_c after proj) | v_t bf16 16M | ksum 512K |
//   wks 64K | Pbuf 1M | Abuf 1M.
// d_out scratch: r_t bf16 [0,16M), w_t bf16 [16M,32M).

#define BB 4
#define TT 2048
#define DD 1024
#define NHH 16
#define HDD 64
#define CC 64
#define LL 32
#define NCH 4096
#define MT (BB * TT)   // 8192 rows
#define ROWP 136       // padded LDS row stride (bf16 elems) for the transpose

using bf16 = __hip_bfloat16;
typedef __attribute__((ext_vector_type(8))) short bfrag8;
typedef __attribute__((ext_vector_type(8))) unsigned short us8;
typedef __attribute__((ext_vector_type(4))) float f32x4;

__device__ __forceinline__ void async_ld16(const bf16* g, bf16* l) {
  __builtin_amdgcn_global_load_lds(
      (const __attribute__((address_space(1))) uint32_t*)g,
      (__attribute__((address_space(3))) uint32_t*)l, 16, 0, 0);
}

__device__ __forceinline__ float sigm(float x) {
  // fast: v_exp_f32 + v_rcp_f32 (~1 ulp each; bf16 rounding downstream dominates)
  return __builtin_amdgcn_rcpf(1.0f + __expf(-x));
}
__device__ __forceinline__ float bf2f(bf16 h) {
  unsigned short u = *reinterpret_cast<unsigned short*>(&h);
  return __uint_as_float((unsigned)u << 16);
}
__device__ __forceinline__ float us2f(unsigned short u) {
  return __uint_as_float((unsigned)u << 16);
}
__device__ __forceinline__ unsigned short f2bfbits(float f) {
  bf16 b = __float2bfloat16(f);
  return *reinterpret_cast<unsigned short*>(&b);
}

// ---- fp32 -> bf16 convert (x + Wr,Wv,Ww,Wo) fused with wksum ----
// blocks [0,12288): convert; blocks [12288,12352): wks[h][c]=sum_j Wk[h*64+j][c]
__global__ __launch_bounds__(256)
void convert_kernel(const float* __restrict__ x,
                    const float* __restrict__ Wr, const float* __restrict__ Wv,
                    const float* __restrict__ Ww, const float* __restrict__ Wo,
                    const float* __restrict__ Wk,
                    bf16* __restrict__ x_c, bf16* __restrict__ W_c,
                    float* __restrict__ wks)
{
  if (blockIdx.x >= 12288) {
    const int gid = (blockIdx.x - 12288) * 256 + threadIdx.x;   // 16384
    const int h = gid >> 10, c = gid & 1023;
    float s = 0.0f;
    for (int j = 0; j < 64; ++j)
      s += Wk[(long)((h << 6) + j) * 1024 + c];
    wks[gid] = s;
    return;
  }
  const long g = (long)blockIdx.x * 256 + threadIdx.x;
  const float* src; bf16* dst; long off4;
  if (g < 2097152) { src = x; dst = x_c; off4 = g; }
  else {
    long gg = g - 2097152;
    int wsel = (int)(gg >> 18);
    off4 = gg & 262143;
    src = (wsel == 0) ? Wr : (wsel == 1) ? Wv : (wsel == 2) ? Ww : Wo;
    dst = W_c + (long)wsel * 1048576;
  }
  float4 f = reinterpret_cast<const float4*>(src)[off4];
  ushort4 pk;
  pk.x = f2bfbits(f.x); pk.y = f2bfbits(f.y);
  pk.z = f2bfbits(f.z); pk.w = f2bfbits(f.w);
  reinterpret_cast<ushort4*>(dst)[off4] = pk;
}

// ---- MFMA GEMM mainloop, BK=64, XOR-chunk staging permutation ----
// LDS row-major [128][64] bf16 (8 chunks of 16B per row).
// Staging: lane l (of a wave issue) covers row (l>>3), phys chunk (l&7),
// fetching GLOBAL chunk (l&7)^((l>>3)&7). Reads fetch phys (kh*4+quad)^(lane15&7).
__device__ __forceinline__ void gemm_mainloop(
    const bf16* __restrict__ A, const bf16* __restrict__ W,
    int blockM, int blockN, bf16* a_sh, bf16* b_sh, f32x4 acc[4][4])
{
  const int tid    = threadIdx.x;
  const int wave   = tid >> 6;
  const int lane   = tid & 63;
  const int lane15 = lane & 15;
  const int quad   = lane >> 4;
  const int waveM  = wave >> 1;
  const int waveN  = wave & 1;
  const int s_row  = (wave << 5) + (lane >> 3);                 // +it*8 below
  const int s_col  = (((lane & 7) ^ ((lane >> 3) & 7)) << 3);   // permuted global chunk

  const bf16* gA = A + ((long)(blockM * 128) + s_row) * 1024 + s_col;
  const bf16* gW = W + ((long)(blockN * 128) + s_row) * 1024 + s_col;
  bf16* la = a_sh + wave * 2048;   // 32 rows x 64 elems per wave
  bf16* lb = b_sh + wave * 2048;

  const int rsw = lane15 & 7;      // read-side xor key (= local row & 7)

  for (int k0 = 0; k0 < 1024; k0 += 64) {
#pragma unroll
    for (int it = 0; it < 4; ++it) {
      async_ld16(gA + k0 + it * 8 * 1024, la + it * 512);
      async_ld16(gW + k0 + it * 8 * 1024, lb + it * 512);
    }
    __syncthreads();
#pragma unroll
    for (int kh = 0; kh < 2; ++kh) {
      bfrag8 af[4], bfv[4];
      const int pc = ((kh * 4 + quad) ^ rsw) << 3;   // phys chunk elem offset
#pragma unroll
      for (int mi = 0; mi < 4; ++mi)
        af[mi] = *reinterpret_cast<const bfrag8*>(a_sh + (waveM*64 + mi*16 + lane15)*64 + pc);
#pragma unroll
      for (int ni = 0; ni < 4; ++ni)
        bfv[ni] = *reinterpret_cast<const bfrag8*>(b_sh + (waveN*64 + ni*16 + lane15)*64 + pc);
#pragma unroll
      for (int mi = 0; mi < 4; ++mi)
#pragma unroll
        for (int ni = 0; ni < 4; ++ni)
          acc[mi][ni] = __builtin_amdgcn_mfma_f32_16x16x32_bf16(af[mi], bfv[ni], acc[mi][ni], 0, 0, 0);
    }
    __syncthreads();
  }
}

// Blocks [0,1536): proj GEMM. mode 0: r=sigm(x Wr^T) 1: v=x Wv^T 2: w=sigm(x Ww^T)*.99
//   XCD-pinned: f = m%8 + 8*(n + 8*(mh + 8*mode)). LDS-transpose epilogue
//   (padded [128][ROWP=136]) -> coalesced time-major stores.
// Blocks [1536,9728): ksum tail (R13-verified body; sh reused as xs[DD]).
//   ksum ⊥ proj (both read only convert outputs) -> co-scheduled, ksum's
//   L2 traffic hides under proj's MFMA phase.
__global__ __launch_bounds__(256, 2)
void proj_kernel(const bf16* __restrict__ X, const bf16* __restrict__ W_c,
                 bf16* __restrict__ r_t, bf16* __restrict__ v_t,
                 bf16* __restrict__ w_t,
                 const float* __restrict__ wks, float* __restrict__ ksum)
{
  __shared__ __align__(16) bf16 sh[128 * ROWP];  // 34816B; mainloop uses first 32KB
  const int tid = threadIdx.x;

  if (blockIdx.x >= 1536) {
    // ---- ksum[b,h,t] = x_row(m) . wks[h] ----
    bf16* xs = sh;
    const int m = blockIdx.x - 1536;
    *reinterpret_cast<ushort4*>(xs + tid*4) =
        *reinterpret_cast<const ushort4*>(X + (long)m * DD + tid*4);
    __syncthreads();
    const int wave = tid >> 6, lane = tid & 63;
    const int b = m >> 11, t = m & (TT - 1);
#pragma unroll
    for (int hi = 0; hi < 4; ++hi) {
      const int h = wave * 4 + hi;
      float acc = 0.0f;
#pragma unroll
      for (int i = 0; i < 16; ++i) {
        const int c = lane + (i << 6);
        acc += bf2f(xs[c]) * wks[h * DD + c];
      }
#pragma unroll
      for (int msk = 1; msk <= 32; msk <<= 1) acc += __shfl_xor(acc, msk);
      if (lane == 0) ksum[((long)(b * NHH + h)) * TT + t] = acc;
    }
    return;
  }

  const int f  = blockIdx.x;
  const int u  = f & 7;
  const int q  = f >> 3;
  const int n  = q & 7;
  const int p  = q >> 3;
  const int mh = p & 7;
  const int mode = p >> 3;
  const int m  = u + (mh << 3);

  const bf16* W = W_c + (long)mode * 1048576;
  f32x4 acc[4][4] = {};
  gemm_mainloop(X, W, m, n, sh, sh + 8192, acc);

  const int wave = tid >> 6, lane = tid & 63;
  const int lane15 = lane & 15, quad = lane >> 4;
  const int waveM = wave >> 1, waveN = wave & 1;
  bf16* outp = (mode == 0) ? r_t : (mode == 1) ? v_t : w_t;

  // stage transposed tile: sh[nn_l][mm_l] with padded stride (quadrants
  // disjoint per wave; mainloop ended with __syncthreads -> safe to overwrite)
#pragma unroll
  for (int mi = 0; mi < 4; ++mi) {
    const int mm0 = waveM*64 + mi*16 + quad*4;
#pragma unroll
    for (int ni = 0; ni < 4; ++ni) {
      const int nn = waveN*64 + ni*16 + lane15;
      float v0 = acc[mi][ni][0], v1 = acc[mi][ni][1];
      float v2 = acc[mi][ni][2], v3 = acc[mi][ni][3];
      if (mode == 0) { v0 = sigm(v0); v1 = sigm(v1); v2 = sigm(v2); v3 = sigm(v3); }
      else if (mode == 2) {
        v0 = sigm(v0)*0.99f; v1 = sigm(v1)*0.99f;
        v2 = sigm(v2)*0.99f; v3 = sigm(v3)*0.99f;
      }
      ushort4 pk;
      pk.x = f2bfbits(v0); pk.y = f2bfbits(v1);
      pk.z = f2bfbits(v2); pk.w = f2bfbits(v3);
      *reinterpret_cast<ushort4*>(sh + nn*ROWP + mm0) = pk;
    }
  }
  __syncthreads();

  // coalesced time-major write-out: pass pp -> rows pp*16+(tid>>4),
  // 16 lanes x us8 cover the row's 128 mm (256B contiguous per row).
  const int nn_base = n * 128;
  const int mm_base = m * 128;
#pragma unroll
  for (int pp = 0; pp < 8; ++pp) {
    const int nn_l = pp*16 + (tid >> 4);
    const int mm_l = (tid & 15) * 8;
    us8 v = *reinterpret_cast<const us8*>(sh + nn_l*ROWP + mm_l);
    *reinterpret_cast<us8*>(outp + (long)(nn_base + nn_l) * MT + (mm_base + mm_l)) = v;
  }
}

// ---- scan A (time-major): per (channel, chunk): P = prod w, A = local scan ----
// grid (64,16) x 256 as R13. Thread (cg,i): channel ch=h*64+i, chunk yb*4+cg.
// Loads: 4x us8 (16B) per array, j contiguous -> MLP-saturated.
__global__ __launch_bounds__(256)
void scanA_kernel(const bf16* __restrict__ v_t, const bf16* __restrict__ w_t,
                  const float* __restrict__ ksum,
                  float* __restrict__ Pbuf, float* __restrict__ Abuf)
{
  __shared__ float ks_sh[128];
  const int bh = blockIdx.x;
  const int b = bh >> 4, h = bh & 15;
  const int tid = threadIdx.x;
  const int i = tid & 63;
  const int cg = tid >> 6;
  const int chunk = blockIdx.y * 4 + cg;
  if (tid < 128) ks_sh[tid] = ksum[(long)bh * TT + blockIdx.y * 128 + tid];
  __syncthreads();
  const int ch = h * HDD + i;
  const long tbase = (long)ch * MT + b * TT + chunk * LL;
  us8 wv[4], vv[4];
#pragma unroll
  for (int q = 0; q < 4; ++q) {
    wv[q] = *reinterpret_cast<const us8*>(w_t + tbase + q*8);
    vv[q] = *reinterpret_cast<const us8*>(v_t + tbase + q*8);
  }
  const float* ksp = ks_sh + cg * LL;
  float s = 0.0f, P = 1.0f;
#pragma unroll
  for (int j = 0; j < LL; ++j) {
    float wf = us2f((unsigned short)wv[j>>3][j&7]);
    float vf = us2f((unsigned short)vv[j>>3][j&7]);
    s = fmaf(wf, s, vf * ksp[j]);
    P *= wf;
  }
  const int chn = bh * 64 + i;
  Pbuf[chunk * NCH + chn] = P;
  Abuf[chunk * NCH + chn] = s;
}

// ---- scan B: wave-per-channel Kogge-Stone over 64 chunk carries.
// grid 1024 x 256: wave w of block handles channel blockIdx.x*4 + w; lane=chunk.
// Also zeroes rowssq (kernel boundary orders it before scanC's atomics).
__global__ __launch_bounds__(256)
void scanB_kernel(const float* __restrict__ Pbuf, float* __restrict__ Abuf,
                  float* __restrict__ rowssq)
{
  const int tid  = threadIdx.x;
  const int lane = tid & 63;                       // = chunk index
  const int wch  = blockIdx.x * 4 + (tid >> 6);    // channel 0..4095
  const int idx  = lane * NCH + wch;
  float p = Pbuf[idx];
  float a = Abuf[idx];
#pragma unroll
  for (int d = 1; d < 64; d <<= 1) {
    float al = __shfl_up(a, d);
    float pl = __shfl_up(p, d);
    if (lane >= d) { a = fmaf(p, al, a); p *= pl; }
  }
  float carry = __shfl_up(a, 1);                   // exclusive prefix
  if (lane == 0) carry = 0.0f;
  Abuf[idx] = carry;                               // column owned by this wave
  if (blockIdx.x < 32) rowssq[blockIdx.x * 256 + tid] = 0.0f;   // 8192 floats
}

// ---- scan C (time-major inputs): re-scan from carry; out = r*s into
//      so[m][d] (row-major for out_gemm); per-row ssq -> rowssq atomics. ----
__global__ __launch_bounds__(256)
void scanC_kernel(const bf16* __restrict__ r_t, const bf16* __restrict__ v_t,
                  const bf16* __restrict__ w_t, const float* __restrict__ ksum,
                  const float* __restrict__ Abuf, bf16* __restrict__ so,
                  float* __restrict__ rowssq)
{
  __shared__ float ks_sh[128];
  const int bh = blockIdx.x;
  const int b = bh >> 4, h = bh & 15;
  const int tid = threadIdx.x;
  const int i = tid & 63;
  const int cg = tid >> 6;
  const int chunk = blockIdx.y * 4 + cg;
  if (tid < 128) ks_sh[tid] = ksum[(long)bh * TT + blockIdx.y * 128 + tid];
  __syncthreads();
  const int ch = h * HDD + i;
  const long tbase = (long)ch * MT + b * TT + chunk * LL;
  us8 wv[4], vv[4], rv[4];
#pragma unroll
  for (int q = 0; q < 4; ++q) {
    wv[q] = *reinterpret_cast<const us8*>(w_t + tbase + q*8);
    vv[q] = *reinterpret_cast<const us8*>(v_t + tbase + q*8);
    rv[q] = *reinterpret_cast<const us8*>(r_t + tbase + q*8);
  }
  const float* ksp = ks_sh + cg * LL;
  const int chn = bh * 64 + i;
  float s = Abuf[chunk * NCH + chn];
  const long obase = (long)(b * TT + chunk * LL) * DD + ch;
#pragma unroll
  for (int j = 0; j < LL; ++j) {
    float wf = us2f((unsigned short)wv[j>>3][j&7]);
    float vf = us2f((unsigned short)vv[j>>3][j&7]);
    float rf = us2f((unsigned short)rv[j>>3][j&7]);
    s = fmaf(wf, s, vf * ksp[j]);
    unsigned short ob = f2bfbits(rf * s);
    *reinterpret_cast<unsigned short*>(so + obase + (long)j * DD) = ob;
    // ssq of the exact bf16-rounded stored value (matches old rmsnorm input)
    float vfo = us2f(ob);
    float ss = vfo * vfo;
#pragma unroll
    for (int msk = 1; msk <= 32; msk <<= 1) ss += __shfl_xor(ss, msk);
    if (i == 0) atomicAdd(&rowssq[b * TT + chunk * LL + j], ss);
  }
}

// ---- out = so @ Wo^T scaled by per-row rsqrt(mean sq), fp32 stores. ----
// 1-D grid 512, XCD-pinned. RMSNorm fused: out[m,:] = scale[m]*(A[m,:] Wo^T).
__global__ __launch_bounds__(256, 2)
void out_gemm_kernel(const bf16* __restrict__ A, const bf16* __restrict__ Wo_c,
                     const float* __restrict__ rowssq, float* __restrict__ out)
{
  __shared__ __align__(16) bf16 a_sh[128*64];
  __shared__ __align__(16) bf16 b_sh[128*64];
  const int f  = blockIdx.x;
  const int u  = f & 7;
  const int q  = f >> 3;
  const int n  = q & 7;
  const int mh = q >> 3;
  const int m  = u + (mh << 3);

  f32x4 acc[4][4] = {};
  gemm_mainloop(A, Wo_c, m, n, a_sh, b_sh, acc);

  const int tid = threadIdx.x;
  const int wave = tid >> 6, lane = tid & 63;
  const int lane15 = lane & 15, quad = lane >> 4;
  const int waveM = wave >> 1, waveN = wave & 1;
  const int m_base = m * 128 + waveM * 64;
  const int n_base = n * 128 + waveN * 64;
#pragma unroll
  for (int mi = 0; mi < 4; ++mi)
#pragma unroll
    for (int r = 0; r < 4; ++r) {
      int mm = m_base + mi*16 + quad*4 + r;
      float sc = rsqrtf(rowssq[mm] * (1.0f / DD) + 1.1920929e-07f);
#pragma unroll
      for (int ni = 0; ni < 4; ++ni) {
        int nn = n_base + ni*16 + lane15;
        out[(long)mm * DD + nn] = acc[mi][ni][r] * sc;
      }
    }
}

extern "C" void kernel_launch(void* const* d_in, const int* in_sizes, int n_in,
                              void* d_out, int out_size, void* d_ws, size_t ws_size,
                              hipStream_t stream) {
  const float* x  = (const float*)d_in[0];
  const float* Wr = (const float*)d_in[1];
  const float* Wk = (const float*)d_in[2];
  const float* Wv = (const float*)d_in[3];
  const float* Ww = (const float*)d_in[4];
  const float* Wo = (const float*)d_in[5];

  const long NELT = (long)BB * TT * DD;            // 8388608
  bf16*  x_c  = (bf16*)d_ws;                       // 16 MiB (scan output reuses)
  bf16*  W_c  = x_c + NELT;                        // 8 MiB
  bf16*  v_t  = W_c + 4 * 1048576;                 // 16 MiB (time-major v)
  float* ksum = (float*)(v_t + NELT);              // 512 KiB
  float* wks  = ksum + (long)BB * NHH * TT;        // 64 KiB
  float* Pbuf = wks + NHH * DD;                    // 1 MiB
  float* Abuf = Pbuf + (long)CC * NCH;             // 1 MiB
  float* rowssq = (float*)W_c;                     // 32 KiB, aliases Wr_c (dead after proj)

  bf16*  r_t  = (bf16*)d_out;                      // d_out scratch (time-major)
  bf16*  w_t  = (bf16*)d_out + NELT;
  bf16*  so   = x_c;                               // scan output [m][d] (x_c dead after ksum)
  float* out  = (float*)d_out;

  convert_kernel<<<dim3(12352), 256, 0, stream>>>(x, Wr, Wv, Ww, Wo, Wk, x_c, W_c, wks);
  proj_kernel<<<dim3(9728), 256, 0, stream>>>(x_c, W_c, r_t, v_t, w_t, wks, ksum);
  scanA_kernel<<<dim3(64, 16), 256, 0, stream>>>(v_t, w_t, ksum, Pbuf, Abuf);
  scanB_kernel<<<dim3(1024), 256, 0, stream>>>(Pbuf, Abuf, rowssq);
  scanC_kernel<<<dim3(64, 16), 256, 0, stream>>>(r_t, v_t, w_t, ksum, Abuf, so, rowssq);
  out_gemm_kernel<<<dim3(512), 256, 0, stream>>>(so, W_c + 3 * 1048576, rowssq, out);
}

// Round 10
// 221.311 us; speedup vs baseline: 1.1641x; 1.0696x over previous
//
#include <hip/hip_runtime.h>
#include <hip/hip_bf16.h>
#include <stdint.h>

// RWKV7-like block: B=4 T=2048 D=1024 NH=16 HD=64.
// Inputs fp32 (order x,Wr,Wk,Wv,Ww,Wo); OUTPUT FP32. Verified thru R19 (absmax .0195).
//
// R20: ksum as MFMA tail blocks. R19 post-mortem: merged dot-product ksum
// tail ran at 2 blocks/CU (inherits proj's 34.8KB static LDS alloc -> R14
// occupancy trap via LDS) => merged dispatch 77us, MfmaUtil 28. Root fix:
// ksum IS a GEMM (x_c[8192x1024] @ wks^T[16x1024]). Replace 8192 dot blocks
// with 128 MFMA blocks (4 waves; wave = 16-row x 16-head tile; 32x
// mfma_16x16x32_bf16, fragment addressing copied from the verified mainloop,
// rsw=0, direct global loads = 16 full lines/instr). 512MB L2 re-read -> 16MB.
// wks produced in BF16 by convert (rel ~0.2% on ksum; absmax margin 3.6x).
// Grid 1536+128=1664. Everything else byte-identical to R19.
// R18 (verified): +8-pad LDS transpose; proj-only 54.1us, conflicts 590K.
// R16 (verified): time-major r/v/w -> scans MLP-saturated (us8 loads).
// R15 lesson: no inter-block sync/fusion (XCD atomics serialize).
// R14 lesson: never shrink tail grids / starve them of occupancy.
// R13: rmsnorm deleted (row scalar folded into out_gemm epilogue via rowssq);
//   scanB = wave-per-channel Kogge-Stone.
// NOTE (R9): SQ_LDS_BANK_CONFLICT ~4/ds_read_b128 is structural; don't chase.
//
// ws (~42.6 MiB): x_c bf16 16M (scan output `so` reuses it) | W_c bf16 8M
//   (rowssq fp32 32K aliases Wr_c after proj) | v_t bf16 16M | ksum 512K |
//   wks_bf bf16 32K (in old 64K wks slot) | Pbuf 1M | Abuf 1M.
// d_out scratch: r_t bf16 [0,16M), w_t bf16 [16M,32M).

#define BB 4
#define TT 2048
#define DD 1024
#define NHH 16
#define HDD 64
#define CC 64
#define LL 32
#define NCH 4096
#define MT (BB * TT)   // 8192 rows
#define ROWP 136       // padded LDS row stride (bf16 elems) for the transpose

using bf16 = __hip_bfloat16;
typedef __attribute__((ext_vector_type(8))) short bfrag8;
typedef __attribute__((ext_vector_type(8))) unsigned short us8;
typedef __attribute__((ext_vector_type(4))) float f32x4;

__device__ __forceinline__ void async_ld16(const bf16* g, bf16* l) {
  __builtin_amdgcn_global_load_lds(
      (const __attribute__((address_space(1))) uint32_t*)g,
      (__attribute__((address_space(3))) uint32_t*)l, 16, 0, 0);
}

__device__ __forceinline__ float sigm(float x) {
  // fast: v_exp_f32 + v_rcp_f32 (~1 ulp each; bf16 rounding downstream dominates)
  return __builtin_amdgcn_rcpf(1.0f + __expf(-x));
}
__device__ __forceinline__ float bf2f(bf16 h) {
  unsigned short u = *reinterpret_cast<unsigned short*>(&h);
  return __uint_as_float((unsigned)u << 16);
}
__device__ __forceinline__ float us2f(unsigned short u) {
  return __uint_as_float((unsigned)u << 16);
}
__device__ __forceinline__ unsigned short f2bfbits(float f) {
  bf16 b = __float2bfloat16(f);
  return *reinterpret_cast<unsigned short*>(&b);
}

// ---- fp32 -> bf16 convert (x + Wr,Wv,Ww,Wo) fused with wksum ----
// blocks [0,12288): convert; blocks [12288,12352): wks_bf[h][c] =
//   bf16( sum_j Wk[h*64+j][c] )  (bf16 for the MFMA-ksum B operand)
__global__ __launch_bounds__(256)
void convert_kernel(const float* __restrict__ x,
                    const float* __restrict__ Wr, const float* __restrict__ Wv,
                    const float* __restrict__ Ww, const float* __restrict__ Wo,
                    const float* __restrict__ Wk,
                    bf16* __restrict__ x_c, bf16* __restrict__ W_c,
                    bf16* __restrict__ wks_bf)
{
  if (blockIdx.x >= 12288) {
    const int gid = (blockIdx.x - 12288) * 256 + threadIdx.x;   // 16384
    const int h = gid >> 10, c = gid & 1023;
    float s = 0.0f;
    for (int j = 0; j < 64; ++j)
      s += Wk[(long)((h << 6) + j) * 1024 + c];
    wks_bf[gid] = __float2bfloat16(s);
    return;
  }
  const long g = (long)blockIdx.x * 256 + threadIdx.x;
  const float* src; bf16* dst; long off4;
  if (g < 2097152) { src = x; dst = x_c; off4 = g; }
  else {
    long gg = g - 2097152;
    int wsel = (int)(gg >> 18);
    off4 = gg & 262143;
    src = (wsel == 0) ? Wr : (wsel == 1) ? Wv : (wsel == 2) ? Ww : Wo;
    dst = W_c + (long)wsel * 1048576;
  }
  float4 f = reinterpret_cast<const float4*>(src)[off4];
  ushort4 pk;
  pk.x = f2bfbits(f.x); pk.y = f2bfbits(f.y);
  pk.z = f2bfbits(f.z); pk.w = f2bfbits(f.w);
  reinterpret_cast<ushort4*>(dst)[off4] = pk;
}

// ---- MFMA GEMM mainloop, BK=64, XOR-chunk staging permutation ----
// LDS row-major [128][64] bf16 (8 chunks of 16B per row).
// Staging: lane l (of a wave issue) covers row (l>>3), phys chunk (l&7),
// fetching GLOBAL chunk (l&7)^((l>>3)&7). Reads fetch phys (kh*4+quad)^(lane15&7).
__device__ __forceinline__ void gemm_mainloop(
    const bf16* __restrict__ A, const bf16* __restrict__ W,
    int blockM, int blockN, bf16* a_sh, bf16* b_sh, f32x4 acc[4][4])
{
  const int tid    = threadIdx.x;
  const int wave   = tid >> 6;
  const int lane   = tid & 63;
  const int lane15 = lane & 15;
  const int quad   = lane >> 4;
  const int waveM  = wave >> 1;
  const int waveN  = wave & 1;
  const int s_row  = (wave << 5) + (lane >> 3);                 // +it*8 below
  const int s_col  = (((lane & 7) ^ ((lane >> 3) & 7)) << 3);   // permuted global chunk

  const bf16* gA = A + ((long)(blockM * 128) + s_row) * 1024 + s_col;
  const bf16* gW = W + ((long)(blockN * 128) + s_row) * 1024 + s_col;
  bf16* la = a_sh + wave * 2048;   // 32 rows x 64 elems per wave
  bf16* lb = b_sh + wave * 2048;

  const int rsw = lane15 & 7;      // read-side xor key (= local row & 7)

  for (int k0 = 0; k0 < 1024; k0 += 64) {
#pragma unroll
    for (int it = 0; it < 4; ++it) {
      async_ld16(gA + k0 + it * 8 * 1024, la + it * 512);
      async_ld16(gW + k0 + it * 8 * 1024, lb + it * 512);
    }
    __syncthreads();
#pragma unroll
    for (int kh = 0; kh < 2; ++kh) {
      bfrag8 af[4], bfv[4];
      const int pc = ((kh * 4 + quad) ^ rsw) << 3;   // phys chunk elem offset
#pragma unroll
      for (int mi = 0; mi < 4; ++mi)
        af[mi] = *reinterpret_cast<const bfrag8*>(a_sh + (waveM*64 + mi*16 + lane15)*64 + pc);
#pragma unroll
      for (int ni = 0; ni < 4; ++ni)
        bfv[ni] = *reinterpret_cast<const bfrag8*>(b_sh + (waveN*64 + ni*16 + lane15)*64 + pc);
#pragma unroll
      for (int mi = 0; mi < 4; ++mi)
#pragma unroll
        for (int ni = 0; ni < 4; ++ni)
          acc[mi][ni] = __builtin_amdgcn_mfma_f32_16x16x32_bf16(af[mi], bfv[ni], acc[mi][ni], 0, 0, 0);
    }
    __syncthreads();
  }
}

// Blocks [0,1536): proj GEMM. mode 0: r=sigm(x Wr^T) 1: v=x Wv^T 2: w=sigm(x Ww^T)*.99
//   XCD-pinned: f = m%8 + 8*(n + 8*(mh + 8*mode)). LDS-transpose epilogue
//   (padded [128][ROWP=136]) -> coalesced time-major stores.
// Blocks [1536,1664): MFMA ksum tail. Wave = one 16-row x 16-head tile:
//   ksum[b,h,t] = x_row . wks[h] via 32x mfma_16x16x32_bf16 (K=1024).
//   Fragment addressing = mainloop pattern with rsw=0, direct global loads
//   (lanes cover 16 rows x 64B = 16 full lines/instr). No LDS used.
__global__ __launch_bounds__(256, 2)
void proj_kernel(const bf16* __restrict__ X, const bf16* __restrict__ W_c,
                 bf16* __restrict__ r_t, bf16* __restrict__ v_t,
                 bf16* __restrict__ w_t,
                 const bf16* __restrict__ wks_bf, float* __restrict__ ksum)
{
  __shared__ __align__(16) bf16 sh[128 * ROWP];  // 34816B; mainloop uses first 32KB
  const int tid = threadIdx.x;

  if (blockIdx.x >= 1536) {
    // ---- MFMA ksum tail ----
    const int kb   = blockIdx.x - 1536;          // 0..127
    const int wave = tid >> 6, lane = tid & 63;
    const int m0   = (kb * 4 + wave) * 16;       // 16-row tile (covers 8192)
    const int kc   = (lane >> 4) * 8;            // quad's 8-elem k-subchunk
    const bf16* xp = X + (long)(m0 + (lane & 15)) * DD + kc;
    const bf16* wp = wks_bf + (lane & 15) * DD + kc;
    f32x4 acc = {};
    for (int k0 = 0; k0 < 1024; k0 += 32) {
      bfrag8 a  = *reinterpret_cast<const bfrag8*>(xp + k0);
      bfrag8 bb = *reinterpret_cast<const bfrag8*>(wp + k0);
      acc = __builtin_amdgcn_mfma_f32_16x16x32_bf16(a, bb, acc, 0, 0, 0);
    }
    // D layout (verified): row=(lane>>4)*4+r -> m_local, col=lane&15 -> h
    const int h = lane & 15;
#pragma unroll
    for (int r = 0; r < 4; ++r) {
      const int m = m0 + (lane >> 4) * 4 + r;
      const int b = m >> 11, t = m & (TT - 1);
      ksum[((long)(b * NHH + h)) * TT + t] = acc[r];
    }
    return;
  }

  const int f  = blockIdx.x;
  const int u  = f & 7;
  const int q  = f >> 3;
  const int n  = q & 7;
  const int p  = q >> 3;
  const int mh = p & 7;
  const int mode = p >> 3;
  const int m  = u + (mh << 3);

  const bf16* W = W_c + (long)mode * 1048576;
  f32x4 acc[4][4] = {};
  gemm_mainloop(X, W, m, n, sh, sh + 8192, acc);

  const int wave = tid >> 6, lane = tid & 63;
  const int lane15 = lane & 15, quad = lane >> 4;
  const int waveM = wave >> 1, waveN = wave & 1;
  bf16* outp = (mode == 0) ? r_t : (mode == 1) ? v_t : w_t;

  // stage transposed tile: sh[nn_l][mm_l] with padded stride (quadrants
  // disjoint per wave; mainloop ended with __syncthreads -> safe to overwrite)
#pragma unroll
  for (int mi = 0; mi < 4; ++mi) {
    const int mm0 = waveM*64 + mi*16 + quad*4;
#pragma unroll
    for (int ni = 0; ni < 4; ++ni) {
      const int nn = waveN*64 + ni*16 + lane15;
      float v0 = acc[mi][ni][0], v1 = acc[mi][ni][1];
      float v2 = acc[mi][ni][2], v3 = acc[mi][ni][3];
      if (mode == 0) { v0 = sigm(v0); v1 = sigm(v1); v2 = sigm(v2); v3 = sigm(v3); }
      else if (mode == 2) {
        v0 = sigm(v0)*0.99f; v1 = sigm(v1)*0.99f;
        v2 = sigm(v2)*0.99f; v3 = sigm(v3)*0.99f;
      }
      ushort4 pk;
      pk.x = f2bfbits(v0); pk.y = f2bfbits(v1);
      pk.z = f2bfbits(v2); pk.w = f2bfbits(v3);
      *reinterpret_cast<ushort4*>(sh + nn*ROWP + mm0) = pk;
    }
  }
  __syncthreads();

  // coalesced time-major write-out: pass pp -> rows pp*16+(tid>>4),
  // 16 lanes x us8 cover the row's 128 mm (256B contiguous per row).
  const int nn_base = n * 128;
  const int mm_base = m * 128;
#pragma unroll
  for (int pp = 0; pp < 8; ++pp) {
    const int nn_l = pp*16 + (tid >> 4);
    const int mm_l = (tid & 15) * 8;
    us8 v = *reinterpret_cast<const us8*>(sh + nn_l*ROWP + mm_l);
    *reinterpret_cast<us8*>(outp + (long)(nn_base + nn_l) * MT + (mm_base + mm_l)) = v;
  }
}

// ---- scan A (time-major): per (channel, chunk): P = prod w, A = local scan ----
// grid (64,16) x 256 as R13. Thread (cg,i): channel ch=h*64+i, chunk yb*4+cg.
// Loads: 4x us8 (16B) per array, j contiguous -> MLP-saturated.
__global__ __launch_bounds__(256)
void scanA_kernel(const bf16* __restrict__ v_t, const bf16* __restrict__ w_t,
                  const float* __restrict__ ksum,
                  float* __restrict__ Pbuf, float* __restrict__ Abuf)
{
  __shared__ float ks_sh[128];
  const int bh = blockIdx.x;
  const int b = bh >> 4, h = bh & 15;
  const int tid = threadIdx.x;
  const int i = tid & 63;
  const int cg = tid >> 6;
  const int chunk = blockIdx.y * 4 + cg;
  if (tid < 128) ks_sh[tid] = ksum[(long)bh * TT + blockIdx.y * 128 + tid];
  __syncthreads();
  const int ch = h * HDD + i;
  const long tbase = (long)ch * MT + b * TT + chunk * LL;
  us8 wv[4], vv[4];
#pragma unroll
  for (int q = 0; q < 4; ++q) {
    wv[q] = *reinterpret_cast<const us8*>(w_t + tbase + q*8);
    vv[q] = *reinterpret_cast<const us8*>(v_t + tbase + q*8);
  }
  const float* ksp = ks_sh + cg * LL;
  float s = 0.0f, P = 1.0f;
#pragma unroll
  for (int j = 0; j < LL; ++j) {
    float wf = us2f((unsigned short)wv[j>>3][j&7]);
    float vf = us2f((unsigned short)vv[j>>3][j&7]);
    s = fmaf(wf, s, vf * ksp[j]);
    P *= wf;
  }
  const int chn = bh * 64 + i;
  Pbuf[chunk * NCH + chn] = P;
  Abuf[chunk * NCH + chn] = s;
}

// ---- scan B: wave-per-channel Kogge-Stone over 64 chunk carries.
// grid 1024 x 256: wave w of block handles channel blockIdx.x*4 + w; lane=chunk.
// Also zeroes rowssq (kernel boundary orders it before scanC's atomics).
__global__ __launch_bounds__(256)
void scanB_kernel(const float* __restrict__ Pbuf, float* __restrict__ Abuf,
                  float* __restrict__ rowssq)
{
  const int tid  = threadIdx.x;
  const int lane = tid & 63;                       // = chunk index
  const int wch  = blockIdx.x * 4 + (tid >> 6);    // channel 0..4095
  const int idx  = lane * NCH + wch;
  float p = Pbuf[idx];
  float a = Abuf[idx];
#pragma unroll
  for (int d = 1; d < 64; d <<= 1) {
    float al = __shfl_up(a, d);
    float pl = __shfl_up(p, d);
    if (lane >= d) { a = fmaf(p, al, a); p *= pl; }
  }
  float carry = __shfl_up(a, 1);                   // exclusive prefix
  if (lane == 0) carry = 0.0f;
  Abuf[idx] = carry;                               // column owned by this wave
  if (blockIdx.x < 32) rowssq[blockIdx.x * 256 + tid] = 0.0f;   // 8192 floats
}

// ---- scan C (time-major inputs): re-scan from carry; out = r*s into
//      so[m][d] (row-major for out_gemm); per-row ssq -> rowssq atomics. ----
__global__ __launch_bounds__(256)
void scanC_kernel(const bf16* __restrict__ r_t, const bf16* __restrict__ v_t,
                  const bf16* __restrict__ w_t, const float* __restrict__ ksum,
                  const float* __restrict__ Abuf, bf16* __restrict__ so,
                  float* __restrict__ rowssq)
{
  __shared__ float ks_sh[128];
  const int bh = blockIdx.x;
  const int b = bh >> 4, h = bh & 15;
  const int tid = threadIdx.x;
  const int i = tid & 63;
  const int cg = tid >> 6;
  const int chunk = blockIdx.y * 4 + cg;
  if (tid < 128) ks_sh[tid] = ksum[(long)bh * TT + blockIdx.y * 128 + tid];
  __syncthreads();
  const int ch = h * HDD + i;
  const long tbase = (long)ch * MT + b * TT + chunk * LL;
  us8 wv[4], vv[4], rv[4];
#pragma unroll
  for (int q = 0; q < 4; ++q) {
    wv[q] = *reinterpret_cast<const us8*>(w_t + tbase + q*8);
    vv[q] = *reinterpret_cast<const us8*>(v_t + tbase + q*8);
    rv[q] = *reinterpret_cast<const us8*>(r_t + tbase + q*8);
  }
  const float* ksp = ks_sh + cg * LL;
  const int chn = bh * 64 + i;
  float s = Abuf[chunk * NCH + chn];
  const long obase = (long)(b * TT + chunk * LL) * DD + ch;
#pragma unroll
  for (int j = 0; j < LL; ++j) {
    float wf = us2f((unsigned short)wv[j>>3][j&7]);
    float vf = us2f((unsigned short)vv[j>>3][j&7]);
    float rf = us2f((unsigned short)rv[j>>3][j&7]);
    s = fmaf(wf, s, vf * ksp[j]);
    unsigned short ob = f2bfbits(rf * s);
    *reinterpret_cast<unsigned short*>(so + obase + (long)j * DD) = ob;
    // ssq of the exact bf16-rounded stored value (matches old rmsnorm input)
    float vfo = us2f(ob);
    float ss = vfo * vfo;
#pragma unroll
    for (int msk = 1; msk <= 32; msk <<= 1) ss += __shfl_xor(ss, msk);
    if (i == 0) atomicAdd(&rowssq[b * TT + chunk * LL + j], ss);
  }
}

// ---- out = so @ Wo^T scaled by per-row rsqrt(mean sq), fp32 stores. ----
// 1-D grid 512, XCD-pinned. RMSNorm fused: out[m,:] = scale[m]*(A[m,:] Wo^T).
__global__ __launch_bounds__(256, 2)
void out_gemm_kernel(const bf16* __restrict__ A, const bf16* __restrict__ Wo_c,
                     const float* __restrict__ rowssq, float* __restrict__ out)
{
  __shared__ __align__(16) bf16 a_sh[128*64];
  __shared__ __align__(16) bf16 b_sh[128*64];
  const int f  = blockIdx.x;
  const int u  = f & 7;
  const int q  = f >> 3;
  const int n  = q & 7;
  const int mh = q >> 3;
  const int m  = u + (mh << 3);

  f32x4 acc[4][4] = {};
  gemm_mainloop(A, Wo_c, m, n, a_sh, b_sh, acc);

  const int tid = threadIdx.x;
  const int wave = tid >> 6, lane = tid & 63;
  const int lane15 = lane & 15, quad = lane >> 4;
  const int waveM = wave >> 1, waveN = wave & 1;
  const int m_base = m * 128 + waveM * 64;
  const int n_base = n * 128 + waveN * 64;
#pragma unroll
  for (int mi = 0; mi < 4; ++mi)
#pragma unroll
    for (int r = 0; r < 4; ++r) {
      int mm = m_base + mi*16 + quad*4 + r;
      float sc = rsqrtf(rowssq[mm] * (1.0f / DD) + 1.1920929e-07f);
#pragma unroll
      for (int ni = 0; ni < 4; ++ni) {
        int nn = n_base + ni*16 + lane15;
        out[(long)mm * DD + nn] = acc[mi][ni][r] * sc;
      }
    }
}

extern "C" void kernel_launch(void* const* d_in, const int* in_sizes, int n_in,
                              void* d_out, int out_size, void* d_ws, size_t ws_size,
                              hipStream_t stream) {
  const float* x  = (const float*)d_in[0];
  const float* Wr = (const float*)d_in[1];
  const float* Wk = (const float*)d_in[2];
  const float* Wv = (const float*)d_in[3];
  const float* Ww = (const float*)d_in[4];
  const float* Wo = (const float*)d_in[5];

  const long NELT = (long)BB * TT * DD;            // 8388608
  bf16*  x_c  = (bf16*)d_ws;                       // 16 MiB (scan output reuses)
  bf16*  W_c  = x_c + NELT;                        // 8 MiB
  bf16*  v_t  = W_c + 4 * 1048576;                 // 16 MiB (time-major v)
  float* ksum = (float*)(v_t + NELT);              // 512 KiB
  bf16*  wks_bf = (bf16*)(ksum + (long)BB * NHH * TT);  // 32 KiB (in old 64K slot)
  float* Pbuf = (float*)(wks_bf + NHH * DD) + 8192;     // 1 MiB (old offset kept)
  float* Abuf = Pbuf + (long)CC * NCH;             // 1 MiB
  float* rowssq = (float*)W_c;                     // 32 KiB, aliases Wr_c (dead after proj)

  bf16*  r_t  = (bf16*)d_out;                      // d_out scratch (time-major)
  bf16*  w_t  = (bf16*)d_out + NELT;
  bf16*  so   = x_c;                               // scan output [m][d] (x_c dead after ksum)
  float* out  = (float*)d_out;

  convert_kernel<<<dim3(12352), 256, 0, stream>>>(x, Wr, Wv, Ww, Wo, Wk, x_c, W_c, wks_bf);
  proj_kernel<<<dim3(1664), 256, 0, stream>>>(x_c, W_c, r_t, v_t, w_t, wks_bf, ksum);
  scanA_kernel<<<dim3(64, 16), 256, 0, stream>>>(v_t, w_t, ksum, Pbuf, Abuf);
  scanB_kernel<<<dim3(1024), 256, 0, stream>>>(Pbuf, Abuf, rowssq);
  scanC_kernel<<<dim3(64, 16), 256, 0, stream>>>(r_t, v_t, w_t, ksum, Abuf, so, rowssq);
  out_gemm_kernel<<<dim3(512), 256, 0, stream>>>(so, W_c + 3 * 1048576, rowssq, out);
}

// Round 11
// 216.399 us; speedup vs baseline: 1.1906x; 1.0227x over previous
//
#include <hip/hip_runtime.h>
#include <hip/hip_bf16.h>
#include <stdint.h>

// RWKV7-like block: B=4 T=2048 D=1024 NH=16 HD=64.
// Inputs fp32 (order x,Wr,Wk,Wv,Ww,Wo); OUTPUT FP32. Verified thru R20 (absmax .0195).
//
// R21: overlap the merged tails by putting them FIRST in the grid.
// R20 post-mortem (e2e 236.7->221.3, win): MFMA-ksum tail cost ~11us not ~3:
// tail blocks were the LAST 128 of 1664 -> started as proj drained (no
// co-resident waves to hide the 32-deep serial MFMA chain + dependent global
// loads). Fixes: (1) ksum blocks 0..127, proj uses f=blockIdx.x-128 (128%8==0
// -> XCD mapping preserved); (2) ksum K-loop split into 2 independent
// accumulator chains (k, k+32), unroll 4 -> 2x MLP, half the dep chain;
// (3) convert's wks tail (64 blocks) also moved to front. fp32 reassociation
// in ksum partials only (R20 showed ksum-path rounding doesn't move absmax).
// R20: ksum as 128 MFMA tail blocks (512MB L2 re-read -> 16MB); wks in bf16.
// R18 (verified): +8-pad LDS transpose; proj-only 54.1us, conflicts 590K.
// R16 (verified): time-major r/v/w -> scans MLP-saturated (us8 loads).
// R15 lesson: no inter-block sync/fusion (XCD atomics serialize).
// R14/R19 lesson: never starve tail work of occupancy (grid or LDS).
// R13: rmsnorm deleted (row scalar folded into out_gemm epilogue via rowssq);
//   scanB = wave-per-channel Kogge-Stone.
// NOTE (R9): SQ_LDS_BANK_CONFLICT ~4/ds_read_b128 is structural; don't chase.
//
// ws (~42.6 MiB): x_c bf16 16M (scan output `so` reuses it) | W_c bf16 8M
//   (rowssq fp32 32K aliases Wr_c after proj) | v_t bf16 16M | ksum 512K |
//   wks_bf bf16 32K (in old 64K wks slot) | Pbuf 1M | Abuf 1M.
// d_out scratch: r_t bf16 [0,16M), w_t bf16 [16M,32M).

#define BB 4
#define TT 2048
#define DD 1024
#define NHH 16
#define HDD 64
#define CC 64
#define LL 32
#define NCH 4096
#define MT (BB * TT)   // 8192 rows
#define ROWP 136       // padded LDS row stride (bf16 elems) for the transpose

using bf16 = __hip_bfloat16;
typedef __attribute__((ext_vector_type(8))) short bfrag8;
typedef __attribute__((ext_vector_type(8))) unsigned short us8;
typedef __attribute__((ext_vector_type(4))) float f32x4;

__device__ __forceinline__ void async_ld16(const bf16* g, bf16* l) {
  __builtin_amdgcn_global_load_lds(
      (const __attribute__((address_space(1))) uint32_t*)g,
      (__attribute__((address_space(3))) uint32_t*)l, 16, 0, 0);
}

__device__ __forceinline__ float sigm(float x) {
  // fast: v_exp_f32 + v_rcp_f32 (~1 ulp each; bf16 rounding downstream dominates)
  return __builtin_amdgcn_rcpf(1.0f + __expf(-x));
}
__device__ __forceinline__ float bf2f(bf16 h) {
  unsigned short u = *reinterpret_cast<unsigned short*>(&h);
  return __uint_as_float((unsigned)u << 16);
}
__device__ __forceinline__ float us2f(unsigned short u) {
  return __uint_as_float((unsigned)u << 16);
}
__device__ __forceinline__ unsigned short f2bfbits(float f) {
  bf16 b = __float2bfloat16(f);
  return *reinterpret_cast<unsigned short*>(&b);
}

// ---- fp32 -> bf16 convert (x + Wr,Wv,Ww,Wo) fused with wksum ----
// blocks [0,64): wks_bf[h][c] = bf16( sum_j Wk[h*64+j][c] )  (FRONT: overlaps
//   with the bulk convert instead of trailing it)
// blocks [64,12352): convert.
__global__ __launch_bounds__(256)
void convert_kernel(const float* __restrict__ x,
                    const float* __restrict__ Wr, const float* __restrict__ Wv,
                    const float* __restrict__ Ww, const float* __restrict__ Wo,
                    const float* __restrict__ Wk,
                    bf16* __restrict__ x_c, bf16* __restrict__ W_c,
                    bf16* __restrict__ wks_bf)
{
  if (blockIdx.x < 64) {
    const int gid = blockIdx.x * 256 + threadIdx.x;   // 16384
    const int h = gid >> 10, c = gid & 1023;
    float s = 0.0f;
    for (int j = 0; j < 64; ++j)
      s += Wk[(long)((h << 6) + j) * 1024 + c];
    wks_bf[gid] = __float2bfloat16(s);
    return;
  }
  const long g = (long)(blockIdx.x - 64) * 256 + threadIdx.x;
  const float* src; bf16* dst; long off4;
  if (g < 2097152) { src = x; dst = x_c; off4 = g; }
  else {
    long gg = g - 2097152;
    int wsel = (int)(gg >> 18);
    off4 = gg & 262143;
    src = (wsel == 0) ? Wr : (wsel == 1) ? Wv : (wsel == 2) ? Ww : Wo;
    dst = W_c + (long)wsel * 1048576;
  }
  float4 f = reinterpret_cast<const float4*>(src)[off4];
  ushort4 pk;
  pk.x = f2bfbits(f.x); pk.y = f2bfbits(f.y);
  pk.z = f2bfbits(f.z); pk.w = f2bfbits(f.w);
  reinterpret_cast<ushort4*>(dst)[off4] = pk;
}

// ---- MFMA GEMM mainloop, BK=64, XOR-chunk staging permutation ----
// LDS row-major [128][64] bf16 (8 chunks of 16B per row).
// Staging: lane l (of a wave issue) covers row (l>>3), phys chunk (l&7),
// fetching GLOBAL chunk (l&7)^((l>>3)&7). Reads fetch phys (kh*4+quad)^(lane15&7).
__device__ __forceinline__ void gemm_mainloop(
    const bf16* __restrict__ A, const bf16* __restrict__ W,
    int blockM, int blockN, bf16* a_sh, bf16* b_sh, f32x4 acc[4][4])
{
  const int tid    = threadIdx.x;
  const int wave   = tid >> 6;
  const int lane   = tid & 63;
  const int lane15 = lane & 15;
  const int quad   = lane >> 4;
  const int waveM  = wave >> 1;
  const int waveN  = wave & 1;
  const int s_row  = (wave << 5) + (lane >> 3);                 // +it*8 below
  const int s_col  = (((lane & 7) ^ ((lane >> 3) & 7)) << 3);   // permuted global chunk

  const bf16* gA = A + ((long)(blockM * 128) + s_row) * 1024 + s_col;
  const bf16* gW = W + ((long)(blockN * 128) + s_row) * 1024 + s_col;
  bf16* la = a_sh + wave * 2048;   // 32 rows x 64 elems per wave
  bf16* lb = b_sh + wave * 2048;

  const int rsw = lane15 & 7;      // read-side xor key (= local row & 7)

  for (int k0 = 0; k0 < 1024; k0 += 64) {
#pragma unroll
    for (int it = 0; it < 4; ++it) {
      async_ld16(gA + k0 + it * 8 * 1024, la + it * 512);
      async_ld16(gW + k0 + it * 8 * 1024, lb + it * 512);
    }
    __syncthreads();
#pragma unroll
    for (int kh = 0; kh < 2; ++kh) {
      bfrag8 af[4], bfv[4];
      const int pc = ((kh * 4 + quad) ^ rsw) << 3;   // phys chunk elem offset
#pragma unroll
      for (int mi = 0; mi < 4; ++mi)
        af[mi] = *reinterpret_cast<const bfrag8*>(a_sh + (waveM*64 + mi*16 + lane15)*64 + pc);
#pragma unroll
      for (int ni = 0; ni < 4; ++ni)
        bfv[ni] = *reinterpret_cast<const bfrag8*>(b_sh + (waveN*64 + ni*16 + lane15)*64 + pc);
#pragma unroll
      for (int mi = 0; mi < 4; ++mi)
#pragma unroll
        for (int ni = 0; ni < 4; ++ni)
          acc[mi][ni] = __builtin_amdgcn_mfma_f32_16x16x32_bf16(af[mi], bfv[ni], acc[mi][ni], 0, 0, 0);
    }
    __syncthreads();
  }
}

// Blocks [0,128): MFMA ksum (FRONT, overlaps proj). Wave = one 16-row x
//   16-head tile: ksum[b,h,t] = x_row . wks[h] via mfma_16x16x32_bf16, K=1024
//   split into 2 independent accumulator chains (k, k+32) for MLP.
// Blocks [128,1664): proj GEMM, f = blockIdx.x - 128 (128%8==0 -> XCD-pinned
//   mapping preserved). mode 0: r=sigm(x Wr^T) 1: v=x Wv^T 2: w=sigm(x Ww^T)*.99
//   LDS-transpose epilogue (padded [128][ROWP=136]) -> coalesced time-major.
__global__ __launch_bounds__(256, 2)
void proj_kernel(const bf16* __restrict__ X, const bf16* __restrict__ W_c,
                 bf16* __restrict__ r_t, bf16* __restrict__ v_t,
                 bf16* __restrict__ w_t,
                 const bf16* __restrict__ wks_bf, float* __restrict__ ksum)
{
  __shared__ __align__(16) bf16 sh[128 * ROWP];  // 34816B; mainloop uses first 32KB
  const int tid = threadIdx.x;

  if (blockIdx.x < 128) {
    // ---- MFMA ksum (dual accumulator chains) ----
    const int kb   = blockIdx.x;                 // 0..127
    const int wave = tid >> 6, lane = tid & 63;
    const int m0   = (kb * 4 + wave) * 16;       // 16-row tile (covers 8192)
    const int kc   = (lane >> 4) * 8;            // quad's 8-elem k-subchunk
    const bf16* xp = X + (long)(m0 + (lane & 15)) * DD + kc;
    const bf16* wp = wks_bf + (lane & 15) * DD + kc;
    f32x4 acc0 = {}, acc1 = {};
#pragma unroll 4
    for (int k0 = 0; k0 < 1024; k0 += 64) {
      bfrag8 a0 = *reinterpret_cast<const bfrag8*>(xp + k0);
      bfrag8 b0 = *reinterpret_cast<const bfrag8*>(wp + k0);
      bfrag8 a1 = *reinterpret_cast<const bfrag8*>(xp + k0 + 32);
      bfrag8 b1 = *reinterpret_cast<const bfrag8*>(wp + k0 + 32);
      acc0 = __builtin_amdgcn_mfma_f32_16x16x32_bf16(a0, b0, acc0, 0, 0, 0);
      acc1 = __builtin_amdgcn_mfma_f32_16x16x32_bf16(a1, b1, acc1, 0, 0, 0);
    }
    // D layout (verified): row=(lane>>4)*4+r -> m_local, col=lane&15 -> h
    const int h = lane & 15;
#pragma unroll
    for (int r = 0; r < 4; ++r) {
      const int m = m0 + (lane >> 4) * 4 + r;
      const int b = m >> 11, t = m & (TT - 1);
      ksum[((long)(b * NHH + h)) * TT + t] = acc0[r] + acc1[r];
    }
    return;
  }

  const int f  = blockIdx.x - 128;
  const int u  = f & 7;
  const int q  = f >> 3;
  const int n  = q & 7;
  const int p  = q >> 3;
  const int mh = p & 7;
  const int mode = p >> 3;
  const int m  = u + (mh << 3);

  const bf16* W = W_c + (long)mode * 1048576;
  f32x4 acc[4][4] = {};
  gemm_mainloop(X, W, m, n, sh, sh + 8192, acc);

  const int wave = tid >> 6, lane = tid & 63;
  const int lane15 = lane & 15, quad = lane >> 4;
  const int waveM = wave >> 1, waveN = wave & 1;
  bf16* outp = (mode == 0) ? r_t : (mode == 1) ? v_t : w_t;

  // stage transposed tile: sh[nn_l][mm_l] with padded stride (quadrants
  // disjoint per wave; mainloop ended with __syncthreads -> safe to overwrite)
#pragma unroll
  for (int mi = 0; mi < 4; ++mi) {
    const int mm0 = waveM*64 + mi*16 + quad*4;
#pragma unroll
    for (int ni = 0; ni < 4; ++ni) {
      const int nn = waveN*64 + ni*16 + lane15;
      float v0 = acc[mi][ni][0], v1 = acc[mi][ni][1];
      float v2 = acc[mi][ni][2], v3 = acc[mi][ni][3];
      if (mode == 0) { v0 = sigm(v0); v1 = sigm(v1); v2 = sigm(v2); v3 = sigm(v3); }
      else if (mode == 2) {
        v0 = sigm(v0)*0.99f; v1 = sigm(v1)*0.99f;
        v2 = sigm(v2)*0.99f; v3 = sigm(v3)*0.99f;
      }
      ushort4 pk;
      pk.x = f2bfbits(v0); pk.y = f2bfbits(v1);
      pk.z = f2bfbits(v2); pk.w = f2bfbits(v3);
      *reinterpret_cast<ushort4*>(sh + nn*ROWP + mm0) = pk;
    }
  }
  __syncthreads();

  // coalesced time-major write-out: pass pp -> rows pp*16+(tid>>4),
  // 16 lanes x us8 cover the row's 128 mm (256B contiguous per row).
  const int nn_base = n * 128;
  const int mm_base = m * 128;
#pragma unroll
  for (int pp = 0; pp < 8; ++pp) {
    const int nn_l = pp*16 + (tid >> 4);
    const int mm_l = (tid & 15) * 8;
    us8 v = *reinterpret_cast<const us8*>(sh + nn_l*ROWP + mm_l);
    *reinterpret_cast<us8*>(outp + (long)(nn_base + nn_l) * MT + (mm_base + mm_l)) = v;
  }
}

// ---- scan A (time-major): per (channel, chunk): P = prod w, A = local scan ----
// grid (64,16) x 256 as R13. Thread (cg,i): channel ch=h*64+i, chunk yb*4+cg.
// Loads: 4x us8 (16B) per array, j contiguous -> MLP-saturated.
__global__ __launch_bounds__(256)
void scanA_kernel(const bf16* __restrict__ v_t, const bf16* __restrict__ w_t,
                  const float* __restrict__ ksum,
                  float* __restrict__ Pbuf, float* __restrict__ Abuf)
{
  __shared__ float ks_sh[128];
  const int bh = blockIdx.x;
  const int b = bh >> 4, h = bh & 15;
  const int tid = threadIdx.x;
  const int i = tid & 63;
  const int cg = tid >> 6;
  const int chunk = blockIdx.y * 4 + cg;
  if (tid < 128) ks_sh[tid] = ksum[(long)bh * TT + blockIdx.y * 128 + tid];
  __syncthreads();
  const int ch = h * HDD + i;
  const long tbase = (long)ch * MT + b * TT + chunk * LL;
  us8 wv[4], vv[4];
#pragma unroll
  for (int q = 0; q < 4; ++q) {
    wv[q] = *reinterpret_cast<const us8*>(w_t + tbase + q*8);
    vv[q] = *reinterpret_cast<const us8*>(v_t + tbase + q*8);
  }
  const float* ksp = ks_sh + cg * LL;
  float s = 0.0f, P = 1.0f;
#pragma unroll
  for (int j = 0; j < LL; ++j) {
    float wf = us2f((unsigned short)wv[j>>3][j&7]);
    float vf = us2f((unsigned short)vv[j>>3][j&7]);
    s = fmaf(wf, s, vf * ksp[j]);
    P *= wf;
  }
  const int chn = bh * 64 + i;
  Pbuf[chunk * NCH + chn] = P;
  Abuf[chunk * NCH + chn] = s;
}

// ---- scan B: wave-per-channel Kogge-Stone over 64 chunk carries.
// grid 1024 x 256: wave w of block handles channel blockIdx.x*4 + w; lane=chunk.
// Also zeroes rowssq (kernel boundary orders it before scanC's atomics).
__global__ __launch_bounds__(256)
void scanB_kernel(const float* __restrict__ Pbuf, float* __restrict__ Abuf,
                  float* __restrict__ rowssq)
{
  const int tid  = threadIdx.x;
  const int lane = tid & 63;                       // = chunk index
  const int wch  = blockIdx.x * 4 + (tid >> 6);    // channel 0..4095
  const int idx  = lane * NCH + wch;
  float p = Pbuf[idx];
  float a = Abuf[idx];
#pragma unroll
  for (int d = 1; d < 64; d <<= 1) {
    float al = __shfl_up(a, d);
    float pl = __shfl_up(p, d);
    if (lane >= d) { a = fmaf(p, al, a); p *= pl; }
  }
  float carry = __shfl_up(a, 1);                   // exclusive prefix
  if (lane == 0) carry = 0.0f;
  Abuf[idx] = carry;                               // column owned by this wave
  if (blockIdx.x < 32) rowssq[blockIdx.x * 256 + tid] = 0.0f;   // 8192 floats
}

// ---- scan C (time-major inputs): re-scan from carry; out = r*s into
//      so[m][d] (row-major for out_gemm); per-row ssq -> rowssq atomics. ----
__global__ __launch_bounds__(256)
void scanC_kernel(const bf16* __restrict__ r_t, const bf16* __restrict__ v_t,
                  const bf16* __restrict__ w_t, const float* __restrict__ ksum,
                  const float* __restrict__ Abuf, bf16* __restrict__ so,
                  float* __restrict__ rowssq)
{
  __shared__ float ks_sh[128];
  const int bh = blockIdx.x;
  const int b = bh >> 4, h = bh & 15;
  const int tid = threadIdx.x;
  const int i = tid & 63;
  const int cg = tid >> 6;
  const int chunk = blockIdx.y * 4 + cg;
  if (tid < 128) ks_sh[tid] = ksum[(long)bh * TT + blockIdx.y * 128 + tid];
  __syncthreads();
  const int ch = h * HDD + i;
  const long tbase = (long)ch * MT + b * TT + chunk * LL;
  us8 wv[4], vv[4], rv[4];
#pragma unroll
  for (int q = 0; q < 4; ++q) {
    wv[q] = *reinterpret_cast<const us8*>(w_t + tbase + q*8);
    vv[q] = *reinterpret_cast<const us8*>(v_t + tbase + q*8);
    rv[q] = *reinterpret_cast<const us8*>(r_t + tbase + q*8);
  }
  const float* ksp = ks_sh + cg * LL;
  const int chn = bh * 64 + i;
  float s = Abuf[chunk * NCH + chn];
  const long obase = (long)(b * TT + chunk * LL) * DD + ch;
#pragma unroll
  for (int j = 0; j < LL; ++j) {
    float wf = us2f((unsigned short)wv[j>>3][j&7]);
    float vf = us2f((unsigned short)vv[j>>3][j&7]);
    float rf = us2f((unsigned short)rv[j>>3][j&7]);
    s = fmaf(wf, s, vf * ksp[j]);
    unsigned short ob = f2bfbits(rf * s);
    *reinterpret_cast<unsigned short*>(so + obase + (long)j * DD) = ob;
    // ssq of the exact bf16-rounded stored value (matches old rmsnorm input)
    float vfo = us2f(ob);
    float ss = vfo * vfo;
#pragma unroll
    for (int msk = 1; msk <= 32; msk <<= 1) ss += __shfl_xor(ss, msk);
    if (i == 0) atomicAdd(&rowssq[b * TT + chunk * LL + j], ss);
  }
}

// ---- out = so @ Wo^T scaled by per-row rsqrt(mean sq), fp32 stores. ----
// 1-D grid 512, XCD-pinned. RMSNorm fused: out[m,:] = scale[m]*(A[m,:] Wo^T).
__global__ __launch_bounds__(256, 2)
void out_gemm_kernel(const bf16* __restrict__ A, const bf16* __restrict__ Wo_c,
                     const float* __restrict__ rowssq, float* __restrict__ out)
{
  __shared__ __align__(16) bf16 a_sh[128*64];
  __shared__ __align__(16) bf16 b_sh[128*64];
  const int f  = blockIdx.x;
  const int u  = f & 7;
  const int q  = f >> 3;
  const int n  = q & 7;
  const int mh = q >> 3;
  const int m  = u + (mh << 3);

  f32x4 acc[4][4] = {};
  gemm_mainloop(A, Wo_c, m, n, a_sh, b_sh, acc);

  const int tid = threadIdx.x;
  const int wave = tid >> 6, lane = tid & 63;
  const int lane15 = lane & 15, quad = lane >> 4;
  const int waveM = wave >> 1, waveN = wave & 1;
  const int m_base = m * 128 + waveM * 64;
  const int n_base = n * 128 + waveN * 64;
#pragma unroll
  for (int mi = 0; mi < 4; ++mi)
#pragma unroll
    for (int r = 0; r < 4; ++r) {
      int mm = m_base + mi*16 + quad*4 + r;
      float sc = rsqrtf(rowssq[mm] * (1.0f / DD) + 1.1920929e-07f);
#pragma unroll
      for (int ni = 0; ni < 4; ++ni) {
        int nn = n_base + ni*16 + lane15;
        out[(long)mm * DD + nn] = acc[mi][ni][r] * sc;
      }
    }
}

extern "C" void kernel_launch(void* const* d_in, const int* in_sizes, int n_in,
                              void* d_out, int out_size, void* d_ws, size_t ws_size,
                              hipStream_t stream) {
  const float* x  = (const float*)d_in[0];
  const float* Wr = (const float*)d_in[1];
  const float* Wk = (const float*)d_in[2];
  const float* Wv = (const float*)d_in[3];
  const float* Ww = (const float*)d_in[4];
  const float* Wo = (const float*)d_in[5];

  const long NELT = (long)BB * TT * DD;            // 8388608
  bf16*  x_c  = (bf16*)d_ws;                       // 16 MiB (scan output reuses)
  bf16*  W_c  = x_c + NELT;                        // 8 MiB
  bf16*  v_t  = W_c + 4 * 1048576;                 // 16 MiB (time-major v)
  float* ksum = (float*)(v_t + NELT);              // 512 KiB
  bf16*  wks_bf = (bf16*)(ksum + (long)BB * NHH * TT);  // 32 KiB (in old 64K slot)
  float* Pbuf = (float*)(wks_bf + NHH * DD) + 8192;     // 1 MiB (old offset kept)
  float* Abuf = Pbuf + (long)CC * NCH;             // 1 MiB
  float* rowssq = (float*)W_c;                     // 32 KiB, aliases Wr_c (dead after proj)

  bf16*  r_t  = (bf16*)d_out;                      // d_out scratch (time-major)
  bf16*  w_t  = (bf16*)d_out + NELT;
  bf16*  so   = x_c;                               // scan output [m][d] (x_c dead after ksum)
  float* out  = (float*)d_out;

  convert_kernel<<<dim3(12352), 256, 0, stream>>>(x, Wr, Wv, Ww, Wo, Wk, x_c, W_c, wks_bf);
  proj_kernel<<<dim3(1664), 256, 0, stream>>>(x_c, W_c, r_t, v_t, w_t, wks_bf, ksum);
  scanA_kernel<<<dim3(64, 16), 256, 0, stream>>>(v_t, w_t, ksum, Pbuf, Abuf);
  scanB_kernel<<<dim3(1024), 256, 0, stream>>>(Pbuf, Abuf, rowssq);
  scanC_kernel<<<dim3(64, 16), 256, 0, stream>>>(r_t, v_t, w_t, ksum, Abuf, so, rowssq);
  out_gemm_kernel<<<dim3(512), 256, 0, stream>>>(so, W_c + 3 * 1048576, rowssq, out);
}